// Round 7
// baseline (16628.069 us; speedup 1.0000x reference)
//
#include <hip/hip_runtime.h>
#include <hip/hip_fp16.h>

// EncoderRNN: V=29, H=1024, L=4, B=64, S=512. Inputs/out are FLOAT32 (proven R1/R2).
#define Vn 29
#define Hn 1024
#define Ln 4
#define Bn 64
#define Sn 512
#define BH (Bn * Hn)
#define NBLK 256

typedef _Float16 half8 __attribute__((ext_vector_type(8)));
typedef _Float16 half4v __attribute__((ext_vector_type(4)));
typedef float f32x16 __attribute__((ext_vector_type(16)));
typedef float f32x4 __attribute__((ext_vector_type(4)));

__device__ __forceinline__ float sigmf(float x) { return 1.0f / (1.0f + __expf(-x)); }
__device__ __forceinline__ float tanhf_(float x) { return 1.0f - 2.0f / (__expf(2.0f * x) + 1.0f); }

// Wave-linear permuted layout for h/y interface buffers (we own both sides):
// element (row r, unit j) lives at half-offset
//   ((j>>4)*2 + (r>>5))*512 + (((j>>3)&1)*32 + (r&31))*8 + (j&7)
// so a K-loop wave-load of one MFMA A-fragment chunk is CONTIGUOUS 1 KB
// (lane l reads base + l*16B), 100% 64B-line utilization, and producers
// write full lines. Bit-permutation of (r[5:0], j[9:0]) -> bijective in BH.
__device__ __forceinline__ int perm_off(int r, int j) {
    return (((j >> 4) * 2 + (r >> 5)) << 9) + ((((j >> 3) & 1) << 5) + (r & 31)) * 8 + (j & 7);
}

// --- LLC-coherent 16B load (bypass L1+L2, device coherence point). R6 lesson:
// cached loads + per-step agent fence = 2x SLOWER (invalidate cost swamps the
// L2-sharing gain). sc0 sc1 direct is the proven interface path.
__device__ __forceinline__ half8 ldg_llc(const _Float16* p) {
    half8 v;
    asm volatile("global_load_dwordx4 %0, %1, off sc0 sc1" : "=v"(v) : "v"(p) : "memory");
    return v;
}
// 8B LLC-coherent load, asm-pinned issue point (hoisted y-carry load).
__device__ __forceinline__ half4v ldg_llc4(const _Float16* p) {
    half4v v;
    asm volatile("global_load_dwordx2 %0, %1, off sc0 sc1" : "=v"(v) : "v"(p) : "memory");
    return v;
}
// Wait until <=CNT vector-mem ops outstanding; ties operands so dependent MFMAs
// cannot be scheduled above the wait. Extra EARLIER VMEM ops are harmless:
// vmcnt retires in issue order, so outstanding<=CNT implies our slot retired.
template <int CNT>
__device__ __forceinline__ void vwait1(half8& a) {
    asm volatile("s_waitcnt vmcnt(%1)" : "+v"(a) : "i"(CNT));
}
template <int CNT>
__device__ __forceinline__ void vwait4(half4v& a) {
    asm volatile("s_waitcnt vmcnt(%1)" : "+v"(a) : "i"(CNT));
}

__device__ __forceinline__ void stg_coh4(_Float16* p, half4v v) {
    union { half4v h; unsigned long long u; } c;
    c.h = v;
    __hip_atomic_store((unsigned long long*)p, c.u, __ATOMIC_RELAXED,
                       __HIP_MEMORY_SCOPE_AGENT);
}

// barrier block: c0[8] padded 32 ints apart (0..255), c1 at [256], gen at [288]
#define BAR_INTS 320

__global__ void init_kernel(const float* __restrict__ bi, const float* __restrict__ bh,
                            const float* __restrict__ emb, int* __restrict__ bar,
                            float* __restrict__ biasf, _Float16* __restrict__ ehi,
                            _Float16* __restrict__ hbh) {
    int i = blockIdx.x * blockDim.x + threadIdx.x;
    int stride = gridDim.x * blockDim.x;
    for (int k = i; k < BAR_INTS; k += stride) bar[k] = 0;
    for (int k = i; k < Ln * 4 * Hn; k += stride) biasf[k] = bi[k] + bh[k];
    for (int k = i; k < Vn * Hn; k += stride)
        ehi[k] = (_Float16)((k < Hn) ? 0.f : emb[k]);  // padding_idx=0 row zero
    for (int k = i; k < 2 * Ln * Bn * Hn; k += stride) hbh[k] = (_Float16)0.f;
}

// Grid barrier, zero cache-maintenance: relaxed agent atomics only (proven R3).
// R1 lesson: all-lane flag polling floods the LLC path -- keep 1 poller/block.
// R6 lesson: NO per-step cache fences.
__device__ __forceinline__ void grid_barrier(int* __restrict__ bar, int bid) {
    asm volatile("s_waitcnt vmcnt(0)" ::: "memory");  // drain this wave's stores
    __syncthreads();
    if (threadIdx.x == 0) {
        int* c0 = bar + (bid & 7) * 32;
        int* c1 = bar + 256;
        int* gen = bar + 288;
        int my = __hip_atomic_load(gen, __ATOMIC_RELAXED, __HIP_MEMORY_SCOPE_AGENT);
        bool rel = false;
        int p = __hip_atomic_fetch_add(c0, 1, __ATOMIC_RELAXED, __HIP_MEMORY_SCOPE_AGENT);
        if (p == 31) {
            int q = __hip_atomic_fetch_add(c1, 1, __ATOMIC_RELAXED, __HIP_MEMORY_SCOPE_AGENT);
            if (q == 7) {  // reset-before-release; vmcnt drain orders resets < gen
                for (int g = 0; g < 8; ++g)
                    __hip_atomic_store(bar + g * 32, 0, __ATOMIC_RELAXED,
                                       __HIP_MEMORY_SCOPE_AGENT);
                __hip_atomic_store(c1, 0, __ATOMIC_RELAXED, __HIP_MEMORY_SCOPE_AGENT);
                asm volatile("s_waitcnt vmcnt(0)" ::: "memory");
                __hip_atomic_store(gen, my + 1, __ATOMIC_RELAXED, __HIP_MEMORY_SCOPE_AGENT);
                rel = true;
            }
        }
        if (!rel) {
            long long t0 = clock64();
            int it = 0;
            while (__hip_atomic_load(gen, __ATOMIC_RELAXED, __HIP_MEMORY_SCOPE_AGENT) == my) {
                __builtin_amdgcn_s_sleep(1);
                if (((++it) & 255) == 0 && clock64() - t0 > 2000000000LL) break;  // escape
            }
        }
    }
    __syncthreads();
}

// ---- R7 re-partition: each block M=32 (one row-half) x N=128 (4 gate-tiles).
// Per-block interface traffic halves (reads only its 32 rows): grid 64->32
// MB/step on the LLC path. Per 1KB A-chunk: 4 MFMAs (was 2) -> 2x compute per
// load. wf[4][16] = 256 regs/wave of weights (unified VGPR+AGPR file, 1
// block/CU). K-loop: 4-deep window (proven), MT=1 only.
template <int KS>
struct KStep {
    static __device__ __forceinline__ void run(const _Float16* a0, half8 (&b0)[4],
                                               const half8 (&wf)[4][16], f32x16 (&acc)[4]) {
        constexpr int slot = KS & 3;
        constexpr int CNT = (KS + 4 < 16) ? 3 : (15 - KS);
        vwait1<CNT>(b0[slot]);
        acc[0] = __builtin_amdgcn_mfma_f32_32x32x16_f16(b0[slot], wf[0][KS], acc[0], 0, 0, 0);
        acc[1] = __builtin_amdgcn_mfma_f32_32x32x16_f16(b0[slot], wf[1][KS], acc[1], 0, 0, 0);
        acc[2] = __builtin_amdgcn_mfma_f32_32x32x16_f16(b0[slot], wf[2][KS], acc[2], 0, 0, 0);
        acc[3] = __builtin_amdgcn_mfma_f32_32x32x16_f16(b0[slot], wf[3][KS], acc[3], 0, 0, 0);
        if constexpr (KS + 4 < 16) b0[slot] = ldg_llc(a0 + (KS + 4) * 1024);
        KStep<KS + 1>::run(a0, b0, wf, acc);
    }
};
template <>
struct KStep<16> {
    static __device__ __forceinline__ void run(const _Float16*, half8 (&)[4],
                                               const half8 (&)[4][16], f32x16 (&)[4]) {}
};

__device__ __forceinline__ void cell_compute_coh(const _Float16* a0, const half8 (&wf)[4][16],
                                                 f32x16 (&acc)[4]) {
#pragma unroll
    for (int g = 0; g < 4; ++g)
#pragma unroll
        for (int r = 0; r < 16; ++r) acc[g][r] = 0.f;
    half8 b0[4];
#pragma unroll
    for (int i = 0; i < 4; ++i) b0[i] = ldg_llc(a0 + i * 1024);
    KStep<0>::run(a0, b0, wf, acc);
}

// plain-cached path (layer-0 embedding reads, row-major ehi)
__device__ __forceinline__ void cell_compute_plain(const _Float16* __restrict__ a0,
                                                   const half8 (&wf)[4][16],
                                                   f32x16 (&acc)[4]) {
#pragma unroll
    for (int g = 0; g < 4; ++g)
#pragma unroll
        for (int r = 0; r < 16; ++r) acc[g][r] = 0.f;
#pragma unroll
    for (int ks = 0; ks < 16; ++ks) {
        half8 x0 = *reinterpret_cast<const half8*>(a0 + ks * 16);
        acc[0] = __builtin_amdgcn_mfma_f32_32x32x16_f16(x0, wf[0][ks], acc[0], 0, 0, 0);
        acc[1] = __builtin_amdgcn_mfma_f32_32x32x16_f16(x0, wf[1][ks], acc[1], 0, 0, 0);
        acc[2] = __builtin_amdgcn_mfma_f32_32x32x16_f16(x0, wf[2][ks], acc[2], 0, 0, 0);
        acc[3] = __builtin_amdgcn_mfma_f32_32x32x16_f16(x0, wf[3][ks], acc[3], 0, 0, 0);
    }
}

// part write: C layout (32x32): n=lane&31, m=4*(lane>>5)+(r&3)+8*(r>>2)
template <bool ADD>
__device__ __forceinline__ void part_write(float (*pw)[128], const f32x16 (&acc)[4],
                                           int lane) {
    const int ln = lane & 31;
#pragma unroll
    for (int g = 0; g < 4; ++g)
#pragma unroll
        for (int r = 0; r < 16; ++r) {
            int m = 4 * (lane >> 5) + (r & 3) + 8 * (r >> 2);
            int n = g * 32 + ln;
            int idx = n ^ ((m & 7) << 2);
            if (ADD) pw[m][idx] += acc[g][r];
            else pw[m][idx] = acc[g][r];
        }
}

// Persistent wavefront LSTM: 256 blocks x 512 threads (8 waves, 1 block/CU).
// Block: layer = cu>>6; q = cu&63; mhalf = q>>5 (rows mhalf*32..+32);
// nslice = q&31 (units nslice*32..+32, all 4 gates => N=128).
// Wave w: K-slice 256 (w<4: y/w_ih, w>=4: h/w_hh).
__global__ __launch_bounds__(512, 2) void lstm_persistent(
    const int* __restrict__ padded_in, const int* __restrict__ in_lengths,
    const float* __restrict__ w_ih, const float* __restrict__ w_hh,
    const float* __restrict__ biasf, int* __restrict__ bar,
    const _Float16* __restrict__ ehi, _Float16* __restrict__ hbh,
    _Float16* __restrict__ ybh, float* __restrict__ out) {
    __shared__ __align__(16) float part[4][32][128];  // 64 KB

    const int cu = blockIdx.x;
    const int layer = cu >> 6;
    const int q = cu & 63;
    const int mhalf = q >> 5;
    const int mbase = mhalf * 32;
    const int j0 = (q & 31) * 32;
    const int tid = threadIdx.x;
    const int wv = tid >> 6;
    const int lane = tid & 63;
    const int ln = lane & 31;
    const int khalf = (lane >> 5) * 8;
    const bool isH = (wv >= 4);
    const int kb = (wv & 3) * 256;

    // ---- one-time weight preload: fp32 -> fp16 frags, 4 gate-tiles x 16 ks
    half8 wf[4][16];
    {
        const float* wsrc = isH ? w_hh : w_ih;
#pragma unroll
        for (int g = 0; g < 4; ++g) {
            const float* rowp =
                wsrc + ((size_t)layer * 4096 + g * 1024 + j0 + ln) * Hn + kb + khalf;
#pragma unroll
            for (int ks = 0; ks < 16; ++ks) {
                f32x4 a = *reinterpret_cast<const f32x4*>(rowp + ks * 16);
                f32x4 b = *reinterpret_cast<const f32x4*>(rowp + ks * 16 + 4);
                half8 h;
                h[0] = (_Float16)a[0]; h[1] = (_Float16)a[1];
                h[2] = (_Float16)a[2]; h[3] = (_Float16)a[3];
                h[4] = (_Float16)b[0]; h[5] = (_Float16)b[1];
                h[6] = (_Float16)b[2]; h[7] = (_Float16)b[3];
                wf[g][ks] = h;
            }
        }
    }

    // epilogue ownership (threads 0..255): local row tid>>3, 4 units (tid&7)*4
    const int brow_l = tid >> 3;
    const int brow = mbase + brow_l;
    const int jcol = (tid & 7) * 4;
    const int J = j0 + jcol;
    const int po = perm_off(brow, J);  // loop-invariant permuted half-offset
    float bias[4][4];
#pragma unroll
    for (int g = 0; g < 4; ++g)
#pragma unroll
        for (int p = 0; p < 4; ++p)
            bias[g][p] = biasf[layer * 4096 + g * 1024 + J + p];

    float creg[4] = {0.f, 0.f, 0.f, 0.f};
    float hreg[4] = {0.f, 0.f, 0.f, 0.f};

    const bool carryOwner = (tid < 256) && (layer > 0) && (layer < 3);

    for (int w = 0; w < Sn + Ln - 1; ++w) {
        const int t = w - layer;
        if (t >= 0 && t < Sn) {
            const int bs = in_lengths[t];
            const int pin = t & 1;
            const int pout = pin ^ 1;
            // upper-row blocks skip the GEMM entirely when their rows are all
            // inactive (bs<=32): saves their interface reads too.
            const bool gemmOn = (mhalf == 0) || (bs > 32);

            // early-issue inactive-row y-carry load (layers 1-2): pinned above
            // the K-loop asm loads so its latency hides under compute.
            half4v ycarry{};
            if (carryOwner && brow >= bs)
                ycarry = ldg_llc4(&ybh[(size_t)(pin * 3 + layer - 1) * BH + po]);

            if (gemmOn) {
                f32x16 acc[4];
                if (!isH && layer == 0) {  // embedding: read-only, cacheable
                    const int ko = kb + khalf;
                    const _Float16* a0 =
                        ehi + (size_t)padded_in[(mbase + ln) * Sn + t] * Hn + ko;
                    cell_compute_plain(a0, wf, acc);
                } else {
                    const _Float16* buf =
                        isH ? (hbh + (size_t)(pin * Ln + layer) * BH)
                            : (ybh + (size_t)(pin * 3 + layer - 1) * BH);
                    const _Float16* a0 = buf + (size_t)kb * 64 + mhalf * 512 + lane * 8;
                    cell_compute_coh(a0, wf, acc);
                }
                if (wv < 4) part_write<false>(part[wv], acc, lane);
                __syncthreads();
                if (wv >= 4) part_write<true>(part[wv - 4], acc, lane);
                __syncthreads();
            }

            if (tid < 256) {
                const bool active = (brow < bs);
                if (gemmOn) {
                    // cross-wave K-reduction + bias
                    float gsum[4][4];
#pragma unroll
                    for (int g = 0; g < 4; ++g) {
                        int nidx = (g * 32 + jcol) ^ ((brow_l & 7) << 2);
                        f32x4 s = *reinterpret_cast<const f32x4*>(&part[0][brow_l][nidx]);
#pragma unroll
                        for (int p2 = 1; p2 < 4; ++p2)
                            s = s + *reinterpret_cast<const f32x4*>(&part[p2][brow_l][nidx]);
#pragma unroll
                        for (int p = 0; p < 4; ++p) gsum[g][p] = s[p] + bias[g][p];
                    }

                    float hold[4], ysum[4];
#pragma unroll
                    for (int p = 0; p < 4; ++p) {
                        float cn = sigmf(gsum[1][p]) * creg[p] +
                                   sigmf(gsum[0][p]) * tanhf_(gsum[2][p]);
                        float hn = sigmf(gsum[3][p]) * tanhf_(cn);
                        hold[p] = hreg[p];
                        if (active) { creg[p] = cn; hreg[p] = hn; }
                        ysum[p] = hreg[p] + hold[p];
                    }
                    {   // h broadcast (fp16, t-parity double buffer, permuted)
                        half4v hh;
#pragma unroll
                        for (int p = 0; p < 4; ++p) hh[p] = (_Float16)hreg[p];
                        stg_coh4(&hbh[(size_t)(pout * Ln + layer) * BH + po], hh);
                    }
                    if (layer < 3) {  // y interface feed (same-parity slot)
                        half4v yh;
                        if (active) {
#pragma unroll
                            for (int p = 0; p < 4; ++p) yh[p] = (_Float16)ysum[p];
                        } else {  // carry incoming y (x_t for l=0) verbatim
                            if (layer == 0) {
                                int ib = padded_in[brow * Sn + t];
                                yh = *reinterpret_cast<const half4v*>(&ehi[(size_t)ib * Hn + J]);
                            } else {
                                yh = ycarry;  // drained by K-loop's vmcnt(0)
                            }
                        }
                        stg_coh4(&ybh[(size_t)(pin * 3 + layer) * BH + po], yh);
                    }
                } else {
                    // all rows inactive: pure carry (h unchanged; y passthrough)
                    half4v hh;
#pragma unroll
                    for (int p = 0; p < 4; ++p) hh[p] = (_Float16)hreg[p];
                    stg_coh4(&hbh[(size_t)(pout * Ln + layer) * BH + po], hh);
                    if (layer < 3) {
                        half4v yh;
                        if (layer == 0) {
                            int ib = padded_in[brow * Sn + t];
                            yh = *reinterpret_cast<const half4v*>(&ehi[(size_t)ib * Hn + J]);
                        } else {
                            vwait4<0>(ycarry);  // no K-loop ran: drain explicitly
                            yh = ycarry;
                        }
                        stg_coh4(&ybh[(size_t)(pin * 3 + layer) * BH + po], yh);
                    }
                }
            }
        }
        grid_barrier(bar, cu);
    }

    if (layer == 3 && tid < 256) {
        f32x4 o;
#pragma unroll
        for (int p = 0; p < 4; ++p) o[p] = hreg[p];
        *reinterpret_cast<f32x4*>(&out[(size_t)brow * Hn + J]) = o;
    }
}

extern "C" void kernel_launch(void* const* d_in, const int* in_sizes, int n_in,
                              void* d_out, int out_size, void* d_ws, size_t ws_size,
                              hipStream_t stream) {
    const int* padded_in = (const int*)d_in[0];
    const int* in_lengths = (const int*)d_in[1];
    const float* emb = (const float*)d_in[2];
    const float* w_ih = (const float*)d_in[3];
    const float* w_hh = (const float*)d_in[4];
    const float* b_ih = (const float*)d_in[5];
    const float* b_hh = (const float*)d_in[6];
    float* outp = (float*)d_out;

    // workspace (~2 MB), all segments 16B-aligned
    char* w = (char*)d_ws;
    int* bar = (int*)w;            w += BAR_INTS * 4;
    float* biasf = (float*)w;      w += (size_t)Ln * 4 * Hn * 4;
    _Float16* ehi = (_Float16*)w;  w += (size_t)Vn * Hn * 2;
    _Float16* hbh = (_Float16*)w;  w += (size_t)2 * Ln * Bn * Hn * 2;
    _Float16* ybh = (_Float16*)w;  w += (size_t)2 * 3 * Bn * Hn * 2;

    init_kernel<<<256, 256, 0, stream>>>(b_ih, b_hh, emb, bar, biasf, ehi, hbh);
    lstm_persistent<<<NBLK, 512, 0, stream>>>(padded_in, in_lengths, w_ih, w_hh, biasf, bar,
                                              ehi, hbh, ybh, outp);
}

// Round 8
// 7513.737 us; speedup vs baseline: 2.2130x; 2.2130x over previous
//
#include <hip/hip_runtime.h>
#include <hip/hip_fp16.h>

// EncoderRNN: V=29, H=1024, L=4, B=64, S=512. Inputs/out are FLOAT32 (proven R1/R2).
#define Vn 29
#define Hn 1024
#define Ln 4
#define Bn 64
#define Sn 512
#define BH (Bn * Hn)
#define NBLK 256

typedef _Float16 half8 __attribute__((ext_vector_type(8)));
typedef _Float16 half4v __attribute__((ext_vector_type(4)));
typedef float f32x16 __attribute__((ext_vector_type(16)));
typedef float f32x4 __attribute__((ext_vector_type(4)));

__device__ __forceinline__ float sigmf(float x) { return 1.0f / (1.0f + __expf(-x)); }
__device__ __forceinline__ float tanhf_(float x) { return 1.0f - 2.0f / (__expf(2.0f * x) + 1.0f); }

// Wave-linear permuted layout for h/y interface buffers (we own both sides):
// element (row r, unit j) lives at half-offset
//   ((j>>4)*2 + (r>>5))*512 + (((j>>3)&1)*32 + (r&31))*8 + (j&7)
// K-loop wave-load of one MFMA A-chunk is CONTIGUOUS 1 KB (lane l reads
// base + l*16B; lane l <-> row l&31), full-line epilogue writes.
__device__ __forceinline__ int perm_off(int r, int j) {
    return (((j >> 4) * 2 + (r >> 5)) << 9) + ((((j >> 3) & 1) << 5) + (r & 31)) * 8 + (j & 7);
}

// --- LLC-coherent 16B load (bypass L1+L2, device coherence point). R6 lesson:
// cached loads + per-step agent fence = 2x SLOWER. sc0 sc1 direct is proven.
__device__ __forceinline__ half8 ldg_llc(const _Float16* p) {
    half8 v;
    asm volatile("global_load_dwordx4 %0, %1, off sc0 sc1" : "=v"(v) : "v"(p) : "memory");
    return v;
}
// 8B LLC-coherent load, asm-pinned issue point (hoisted y-carry load).
__device__ __forceinline__ half4v ldg_llc4(const _Float16* p) {
    half4v v;
    asm volatile("global_load_dwordx2 %0, %1, off sc0 sc1" : "=v"(v) : "v"(p) : "memory");
    return v;
}
// Wait until <=CNT vector-mem ops outstanding; ties operands so dependent MFMAs
// cannot be scheduled above the wait. Extra EARLIER VMEM ops are harmless:
// vmcnt retires in issue order.
template <int CNT>
__device__ __forceinline__ void vwait1(half8& a) {
    asm volatile("s_waitcnt vmcnt(%1)" : "+v"(a) : "i"(CNT));
}
template <int CNT>
__device__ __forceinline__ void vwait2(half8& a, half8& b) {
    asm volatile("s_waitcnt vmcnt(%2)" : "+v"(a), "+v"(b) : "i"(CNT));
}

__device__ __forceinline__ void stg_coh4(_Float16* p, half4v v) {
    union { half4v h; unsigned long long u; } c;
    c.h = v;
    __hip_atomic_store((unsigned long long*)p, c.u, __ATOMIC_RELAXED,
                       __HIP_MEMORY_SCOPE_AGENT);
}

// barrier block: c0[8] padded 32 ints apart (0..255), c1 at [256], gen at [288]
#define BAR_INTS 320

__global__ void init_kernel(const float* __restrict__ bi, const float* __restrict__ bh,
                            const float* __restrict__ emb, int* __restrict__ bar,
                            float* __restrict__ biasf, _Float16* __restrict__ ehi,
                            _Float16* __restrict__ hbh) {
    int i = blockIdx.x * blockDim.x + threadIdx.x;
    int stride = gridDim.x * blockDim.x;
    for (int k = i; k < BAR_INTS; k += stride) bar[k] = 0;
    for (int k = i; k < Ln * 4 * Hn; k += stride) biasf[k] = bi[k] + bh[k];
    for (int k = i; k < Vn * Hn; k += stride)
        ehi[k] = (_Float16)((k < Hn) ? 0.f : emb[k]);  // padding_idx=0 row zero
    for (int k = i; k < 2 * Ln * Bn * Hn; k += stride) hbh[k] = (_Float16)0.f;
}

// Grid barrier, zero cache-maintenance: relaxed agent atomics only (proven R3).
// R1: no all-lane polling. R6: no per-step cache fences.
__device__ __forceinline__ void grid_barrier(int* __restrict__ bar, int bid) {
    asm volatile("s_waitcnt vmcnt(0)" ::: "memory");  // drain this wave's stores
    __syncthreads();
    if (threadIdx.x == 0) {
        int* c0 = bar + (bid & 7) * 32;
        int* c1 = bar + 256;
        int* gen = bar + 288;
        int my = __hip_atomic_load(gen, __ATOMIC_RELAXED, __HIP_MEMORY_SCOPE_AGENT);
        bool rel = false;
        int p = __hip_atomic_fetch_add(c0, 1, __ATOMIC_RELAXED, __HIP_MEMORY_SCOPE_AGENT);
        if (p == 31) {
            int q = __hip_atomic_fetch_add(c1, 1, __ATOMIC_RELAXED, __HIP_MEMORY_SCOPE_AGENT);
            if (q == 7) {  // reset-before-release; vmcnt drain orders resets < gen
                for (int g = 0; g < 8; ++g)
                    __hip_atomic_store(bar + g * 32, 0, __ATOMIC_RELAXED,
                                       __HIP_MEMORY_SCOPE_AGENT);
                __hip_atomic_store(c1, 0, __ATOMIC_RELAXED, __HIP_MEMORY_SCOPE_AGENT);
                asm volatile("s_waitcnt vmcnt(0)" ::: "memory");
                __hip_atomic_store(gen, my + 1, __ATOMIC_RELAXED, __HIP_MEMORY_SCOPE_AGENT);
                rel = true;
            }
        }
        if (!rel) {
            long long t0 = clock64();
            int it = 0;
            while (__hip_atomic_load(gen, __ATOMIC_RELAXED, __HIP_MEMORY_SCOPE_AGENT) == my) {
                __builtin_amdgcn_s_sleep(1);
                if (((++it) & 255) == 0 && clock64() - t0 > 2000000000LL) break;  // escape
            }
        }
    }
    __syncthreads();
}

// ---- software-pipelined coherent K-loop: window of 4 chunk-pairs in flight.
// R2/R7 lesson: register budget is EXACTLY full at wf[2][16] (128 VGPR) --
// no deeper window, no wider N. Permuted layout: ks stride 1024 halves.
template <int KS, int MT>
struct KStep {
    static __device__ __forceinline__ void run(const _Float16* a0, const _Float16* a1,
                                               half8 (&b0)[4], half8 (&b1)[4],
                                               const half8 (&wf)[2][16],
                                               f32x16 (&acc)[MT][2]) {
        constexpr int slot = KS & 3;
        constexpr int CNT = MT * ((KS + 4 < 16) ? 3 : (15 - KS));
        if constexpr (MT == 2) vwait2<CNT>(b0[slot], b1[slot]);
        else vwait1<CNT>(b0[slot]);
        acc[0][0] = __builtin_amdgcn_mfma_f32_32x32x16_f16(b0[slot], wf[0][KS], acc[0][0], 0, 0, 0);
        acc[0][1] = __builtin_amdgcn_mfma_f32_32x32x16_f16(b0[slot], wf[1][KS], acc[0][1], 0, 0, 0);
        if constexpr (MT == 2) {
            acc[1][0] = __builtin_amdgcn_mfma_f32_32x32x16_f16(b1[slot], wf[0][KS], acc[1][0], 0, 0, 0);
            acc[1][1] = __builtin_amdgcn_mfma_f32_32x32x16_f16(b1[slot], wf[1][KS], acc[1][1], 0, 0, 0);
        }
        if constexpr (KS + 4 < 16) {
            b0[slot] = ldg_llc(a0 + (KS + 4) * 1024);
            if constexpr (MT == 2) b1[slot] = ldg_llc(a1 + (KS + 4) * 1024);
        }
        KStep<KS + 1, MT>::run(a0, a1, b0, b1, wf, acc);
    }
};
template <int MT>
struct KStep<16, MT> {
    static __device__ __forceinline__ void run(const _Float16*, const _Float16*, half8 (&)[4],
                                               half8 (&)[4], const half8 (&)[2][16],
                                               f32x16 (&)[MT][2]) {}
};

template <int MT>
__device__ __forceinline__ void cell_compute_coh(const _Float16* a0, const _Float16* a1,
                                                 const half8 (&wf)[2][16],
                                                 f32x16 (&acc)[MT][2]) {
#pragma unroll
    for (int mt = 0; mt < MT; ++mt)
#pragma unroll
        for (int nt = 0; nt < 2; ++nt)
#pragma unroll
            for (int r = 0; r < 16; ++r) acc[mt][nt][r] = 0.f;
    half8 b0[4], b1[4];
#pragma unroll
    for (int i = 0; i < 4; ++i) {
        b0[i] = ldg_llc(a0 + i * 1024);
        if constexpr (MT == 2) b1[i] = ldg_llc(a1 + i * 1024);
    }
    KStep<0, MT>::run(a0, a1, b0, b1, wf, acc);
}

// plain-cached path (layer-0 embedding reads, row-major ehi)
template <int MT>
__device__ __forceinline__ void cell_compute_plain(const _Float16* __restrict__ a0,
                                                   const _Float16* __restrict__ a1,
                                                   const half8 (&wf)[2][16],
                                                   f32x16 (&acc)[MT][2]) {
#pragma unroll
    for (int mt = 0; mt < MT; ++mt)
#pragma unroll
        for (int nt = 0; nt < 2; ++nt)
#pragma unroll
            for (int r = 0; r < 16; ++r) acc[mt][nt][r] = 0.f;
#pragma unroll
    for (int ks = 0; ks < 16; ++ks) {
        half8 x0 = *reinterpret_cast<const half8*>(a0 + ks * 16);
        acc[0][0] = __builtin_amdgcn_mfma_f32_32x32x16_f16(x0, wf[0][ks], acc[0][0], 0, 0, 0);
        acc[0][1] = __builtin_amdgcn_mfma_f32_32x32x16_f16(x0, wf[1][ks], acc[0][1], 0, 0, 0);
        if constexpr (MT == 2) {
            half8 x1 = *reinterpret_cast<const half8*>(a1 + ks * 16);
            acc[1][0] = __builtin_amdgcn_mfma_f32_32x32x16_f16(x1, wf[0][ks], acc[1][0], 0, 0, 0);
            acc[1][1] = __builtin_amdgcn_mfma_f32_32x32x16_f16(x1, wf[1][ks], acc[1][1], 0, 0, 0);
        }
    }
}

// part write: C layout (32x32): n=lane&31, m=4*(lane>>5)+(r&3)+8*(r>>2)
template <int MT, bool ADD>
__device__ __forceinline__ void part_write(float (*pw)[64], const f32x16 (&acc)[MT][2],
                                           int lane) {
    const int ln = lane & 31;
#pragma unroll
    for (int mt = 0; mt < MT; ++mt)
#pragma unroll
        for (int nt = 0; nt < 2; ++nt)
#pragma unroll
            for (int r = 0; r < 16; ++r) {
                int m = mt * 32 + 4 * (lane >> 5) + (r & 3) + 8 * (r >> 2);
                int n = nt * 32 + ln;
                int idx = n ^ ((m & 7) << 2);
                if (ADD) pw[m][idx] += acc[mt][nt][r];
                else pw[m][idx] = acc[mt][nt][r];
            }
}

// Persistent wavefront LSTM: 256 blocks x 512 threads (8 waves, 2/SIMD).
// Wave w: K-slice 256 (w<4: y/w_ih, w>=4: h/w_hh), full N=64.
__global__ __launch_bounds__(512, 2) void lstm_persistent(
    const int* __restrict__ padded_in, const int* __restrict__ in_lengths,
    const float* __restrict__ w_ih, const float* __restrict__ w_hh,
    const float* __restrict__ biasf, int* __restrict__ bar,
    const _Float16* __restrict__ ehi, _Float16* __restrict__ hbh,
    _Float16* __restrict__ ybh, float* __restrict__ out) {
    __shared__ __align__(16) float part[4][64][64];  // 64 KB

    const int cu = blockIdx.x;
    const int layer = cu >> 6;
    const int j0 = (cu & 63) * 16;
    const int tid = threadIdx.x;
    const int wv = tid >> 6;
    const int lane = tid & 63;
    const int ln = lane & 31;
    const int khalf = (lane >> 5) * 8;
    const bool isH = (wv >= 4);
    const int kb = (isH ? (wv - 4) : wv) * 256;

    // ---- one-time weight preload: fp32 -> fp16 frags, 128 VGPR/lane
    half8 wf[2][16];
    {
        const float* wsrc = isH ? w_hh : w_ih;
#pragma unroll
        for (int nt = 0; nt < 2; ++nt) {
            int n = nt * 32 + ln;
            const float* rowp =
                wsrc + ((size_t)layer * 4 * Hn + (n >> 4) * Hn + j0 + (n & 15)) * Hn + kb + khalf;
#pragma unroll
            for (int ks = 0; ks < 16; ++ks) {
                f32x4 a = *reinterpret_cast<const f32x4*>(rowp + ks * 16);
                f32x4 b = *reinterpret_cast<const f32x4*>(rowp + ks * 16 + 4);
                half8 h;
                h[0] = (_Float16)a[0]; h[1] = (_Float16)a[1];
                h[2] = (_Float16)a[2]; h[3] = (_Float16)a[3];
                h[4] = (_Float16)b[0]; h[5] = (_Float16)b[1];
                h[6] = (_Float16)b[2]; h[7] = (_Float16)b[3];
                wf[nt][ks] = h;
            }
        }
    }

    // epilogue ownership (threads 0..255): batch row brow, 4 units jcol..jcol+3
    const int brow = (tid & 255) >> 2;
    const int jcol = (tid & 3) * 4;
    const int J = j0 + jcol;
    const int po = perm_off(brow, J);  // loop-invariant permuted half-offset
    float bias[4][4];
#pragma unroll
    for (int g = 0; g < 4; ++g)
#pragma unroll
        for (int p = 0; p < 4; ++p)
            bias[g][p] = biasf[layer * 4096 + g * 1024 + J + p];

    float creg[4] = {0.f, 0.f, 0.f, 0.f};
    float hreg[4] = {0.f, 0.f, 0.f, 0.f};

    const bool carryOwner = (tid < 256) && (layer > 0) && (layer < 3);

    for (int w = 0; w < Sn + Ln - 1; ++w) {
        const int t = w - layer;
        if (t >= 0 && t < Sn) {
            const int bs = in_lengths[t];
            const int pin = t & 1;
            const int pout = pin ^ 1;

            // R8 exact row masking: rows >= bs produce DISCARDED gates (sorted
            // lengths -> active rows are a prefix). Redirect inactive lanes
            // (lane l <-> row l&31 in the permuted chunk) to the chunk's row 0;
            // redirected lanes coalesce onto already-fetched lines, so LLC
            // interface bytes ~ bs exactly (was 32-granular: E 48 -> 32.5 rows).
            const int lim0 = bs < 32 ? bs : 32;
            const int lim1 = bs - 32;  // only consumed when MT==2 (bs>32)
            const int off0 = (ln < lim0) ? lane * 8 : (lane & 32) * 8;
            const int off1 = (ln < lim1) ? lane * 8 : (lane & 32) * 8;

            // early-issue inactive-row y-carry load (layers 1-2, inactive rows
            // only): pinned above the K-loop asm loads; latency hides under
            // compute; drained by the K-loop's terminal vmcnt(0)-equivalent.
            half4v ycarry{};
            if (carryOwner && brow >= bs)
                ycarry = ldg_llc4(&ybh[(size_t)(pin * 3 + layer - 1) * BH + po]);

            // per-wave A-source pointers for its K-slice (permuted layout:
            // chunk base + kb*64; ks stride 1024; chunk1 (rows 32-63) +512)
            const _Float16 *a0, *a1;
            bool coh;
            if (!isH) {
                if (layer == 0) {  // embedding: read-only, cacheable, row-major
                    const int ko = kb + khalf;
                    a0 = ehi + (size_t)padded_in[ln * Sn + t] * Hn + ko;
                    a1 = ehi + (size_t)padded_in[(32 + ln) * Sn + t] * Hn + ko;
                    coh = false;
                } else {
                    const _Float16* cb =
                        ybh + (size_t)(pin * 3 + layer - 1) * BH + (size_t)kb * 64;
                    a0 = cb + off0;
                    a1 = cb + 512 + off1;
                    coh = true;
                }
            } else {
                const _Float16* cb =
                    hbh + (size_t)(pin * Ln + layer) * BH + (size_t)kb * 64;
                a0 = cb + off0;
                a1 = cb + 512 + off1;
                coh = true;
            }

            // compute; two-phase partial accumulation (waves 0-3 store, 4-7 add)
            if (bs > 32) {
                f32x16 acc[2][2];
                if (coh) cell_compute_coh<2>(a0, a1, wf, acc);
                else cell_compute_plain<2>(a0, a1, wf, acc);
                if (wv < 4) part_write<2, false>(part[wv], acc, lane);
                __syncthreads();
                if (wv >= 4) part_write<2, true>(part[wv - 4], acc, lane);
            } else {
                f32x16 acc[1][2];
                if (coh) cell_compute_coh<1>(a0, a1, wf, acc);
                else cell_compute_plain<1>(a0, a1, wf, acc);
                if (wv < 4) part_write<1, false>(part[wv], acc, lane);
                __syncthreads();
                if (wv >= 4) part_write<1, true>(part[wv - 4], acc, lane);
            }
            __syncthreads();

            if (tid < 256) {
                // cross-wave K-reduction + bias
                float gsum[4][4];
#pragma unroll
                for (int g = 0; g < 4; ++g) {
                    int nidx = (g * 16 + jcol) ^ ((brow & 7) << 2);
                    f32x4 s = *reinterpret_cast<const f32x4*>(&part[0][brow][nidx]);
#pragma unroll
                    for (int p2 = 1; p2 < 4; ++p2)
                        s = s + *reinterpret_cast<const f32x4*>(&part[p2][brow][nidx]);
#pragma unroll
                    for (int p = 0; p < 4; ++p) gsum[g][p] = s[p] + bias[g][p];
                }

                const bool active = (brow < bs);
                float hold[4], ysum[4];
#pragma unroll
                for (int p = 0; p < 4; ++p) {
                    float cn = sigmf(gsum[1][p]) * creg[p] + sigmf(gsum[0][p]) * tanhf_(gsum[2][p]);
                    float hn = sigmf(gsum[3][p]) * tanhf_(cn);
                    hold[p] = hreg[p];
                    if (active) { creg[p] = cn; hreg[p] = hn; }
                    ysum[p] = hreg[p] + hold[p];
                }
                {   // h broadcast (fp16, t-parity double buffer, permuted) -> LLC
                    half4v hh;
#pragma unroll
                    for (int p = 0; p < 4; ++p) hh[p] = (_Float16)hreg[p];
                    stg_coh4(&hbh[(size_t)(pout * Ln + layer) * BH + po], hh);
                }
                if (layer < 3) {  // y interface feed (same-parity slot, permuted) -> LLC
                    half4v yh;
                    if (active) {
#pragma unroll
                        for (int p = 0; p < 4; ++p) yh[p] = (_Float16)ysum[p];
                    } else {  // carry incoming y (x_t for l=0) verbatim
                        if (layer == 0) {
                            int ib = padded_in[brow * Sn + t];
                            yh = *reinterpret_cast<const half4v*>(&ehi[(size_t)ib * Hn + J]);
                        } else {
                            yh = ycarry;  // pre-issued at step start
                        }
                    }
                    stg_coh4(&ybh[(size_t)(pin * 3 + layer) * BH + po], yh);
                }
            }
        }
        grid_barrier(bar, cu);
    }

    if (layer == 3 && tid < 256) {
        f32x4 o;
#pragma unroll
        for (int p = 0; p < 4; ++p) o[p] = hreg[p];
        *reinterpret_cast<f32x4*>(&out[(size_t)brow * Hn + J]) = o;
    }
}

extern "C" void kernel_launch(void* const* d_in, const int* in_sizes, int n_in,
                              void* d_out, int out_size, void* d_ws, size_t ws_size,
                              hipStream_t stream) {
    const int* padded_in = (const int*)d_in[0];
    const int* in_lengths = (const int*)d_in[1];
    const float* emb = (const float*)d_in[2];
    const float* w_ih = (const float*)d_in[3];
    const float* w_hh = (const float*)d_in[4];
    const float* b_ih = (const float*)d_in[5];
    const float* b_hh = (const float*)d_in[6];
    float* outp = (float*)d_out;

    // workspace (~2 MB), all segments 16B-aligned
    char* w = (char*)d_ws;
    int* bar = (int*)w;            w += BAR_INTS * 4;
    float* biasf = (float*)w;      w += (size_t)Ln * 4 * Hn * 4;
    _Float16* ehi = (_Float16*)w;  w += (size_t)Vn * Hn * 2;
    _Float16* hbh = (_Float16*)w;  w += (size_t)2 * Ln * Bn * Hn * 2;
    _Float16* ybh = (_Float16*)w;  w += (size_t)2 * 3 * Bn * Hn * 2;

    init_kernel<<<256, 256, 0, stream>>>(b_ih, b_hh, emb, bar, biasf, ehi, hbh);
    lstm_persistent<<<NBLK, 512, 0, stream>>>(padded_in, in_lengths, w_ih, w_hh, biasf, bar,
                                              ehi, hbh, ybh, outp);
}

// Round 11
// 7377.811 us; speedup vs baseline: 2.2538x; 1.0184x over previous
//
#include <hip/hip_runtime.h>
#include <hip/hip_fp16.h>

// EncoderRNN: V=29, H=1024, L=4, B=64, S=512. Inputs/out are FLOAT32 (proven R1/R2).
#define Vn 29
#define Hn 1024
#define Ln 4
#define Bn 64
#define Sn 512
#define BH (Bn * Hn)
#define NBLK 256

typedef _Float16 half8 __attribute__((ext_vector_type(8)));
typedef _Float16 half4v __attribute__((ext_vector_type(4)));
typedef float f32x16 __attribute__((ext_vector_type(16)));
typedef float f32x4 __attribute__((ext_vector_type(4)));

__device__ __forceinline__ float sigmf(float x) { return 1.0f / (1.0f + __expf(-x)); }
__device__ __forceinline__ float tanhf_(float x) { return 1.0f - 2.0f / (__expf(2.0f * x) + 1.0f); }

// Wave-linear permuted layout for h/y interface buffers (we own both sides):
// element (row r, unit j) lives at half-offset
//   ((j>>4)*2 + (r>>5))*512 + (((j>>3)&1)*32 + (r&31))*8 + (j&7)
// K-loop wave-load of one MFMA A-chunk is CONTIGUOUS 1 KB (lane l reads
// base + l*16B; lane l <-> row l&31), full-line epilogue writes.
__device__ __forceinline__ int perm_off(int r, int j) {
    return (((j >> 4) * 2 + (r >> 5)) << 9) + ((((j >> 3) & 1) << 5) + (r & 31)) * 8 + (j & 7);
}

// --- LLC-coherent 16B load (bypass L1+L2, device coherence point). R6 lesson:
// cached loads + per-step agent fence = 2x SLOWER. sc0 sc1 direct is proven.
__device__ __forceinline__ half8 ldg_llc(const _Float16* p) {
    half8 v;
    asm volatile("global_load_dwordx4 %0, %1, off sc0 sc1" : "=v"(v) : "v"(p) : "memory");
    return v;
}
// 8B LLC-coherent load, asm-pinned issue point (hoisted y-carry load).
__device__ __forceinline__ half4v ldg_llc4(const _Float16* p) {
    half4v v;
    asm volatile("global_load_dwordx2 %0, %1, off sc0 sc1" : "=v"(v) : "v"(p) : "memory");
    return v;
}
// Wait until <=CNT vector-mem ops outstanding; ties operands so dependent MFMAs
// cannot be scheduled above the wait. Extra EARLIER VMEM ops are harmless:
// vmcnt retires in issue order.
template <int CNT>
__device__ __forceinline__ void vwait1(half8& a) {
    asm volatile("s_waitcnt vmcnt(%1)" : "+v"(a) : "i"(CNT));
}
template <int CNT>
__device__ __forceinline__ void vwait2(half8& a, half8& b) {
    asm volatile("s_waitcnt vmcnt(%2)" : "+v"(a), "+v"(b) : "i"(CNT));
}

__device__ __forceinline__ void stg_coh4(_Float16* p, half4v v) {
    union { half4v h; unsigned long long u; } c;
    c.h = v;
    __hip_atomic_store((unsigned long long*)p, c.u, __ATOMIC_RELAXED,
                       __HIP_MEMORY_SCOPE_AGENT);
}

// barrier block: c0[8] padded 32 ints apart (0..255), c1 at [256], gen at [288]
#define BAR_INTS 320

__global__ void init_kernel(const float* __restrict__ bi, const float* __restrict__ bh,
                            const float* __restrict__ emb, int* __restrict__ bar,
                            float* __restrict__ biasf, _Float16* __restrict__ ehi,
                            _Float16* __restrict__ hbh) {
    int i = blockIdx.x * blockDim.x + threadIdx.x;
    int stride = gridDim.x * blockDim.x;
    for (int k = i; k < BAR_INTS; k += stride) bar[k] = 0;
    for (int k = i; k < Ln * 4 * Hn; k += stride) biasf[k] = bi[k] + bh[k];
    for (int k = i; k < Vn * Hn; k += stride)
        ehi[k] = (_Float16)((k < Hn) ? 0.f : emb[k]);  // padding_idx=0 row zero
    for (int k = i; k < 2 * Ln * Bn * Hn; k += stride) hbh[k] = (_Float16)0.f;
}

// Grid barrier, zero cache-maintenance: relaxed agent atomics only.
// PROVEN protocol (R2/R3/R8 pass; R9/R10 aggregator redesign faulted twice --
// do NOT touch this). R1: no all-lane polling. R6: no per-step cache fences.
__device__ __forceinline__ void grid_barrier(int* __restrict__ bar, int bid) {
    asm volatile("s_waitcnt vmcnt(0)" ::: "memory");  // drain this wave's stores
    __syncthreads();
    if (threadIdx.x == 0) {
        int* c0 = bar + (bid & 7) * 32;
        int* c1 = bar + 256;
        int* gen = bar + 288;
        int my = __hip_atomic_load(gen, __ATOMIC_RELAXED, __HIP_MEMORY_SCOPE_AGENT);
        bool rel = false;
        int p = __hip_atomic_fetch_add(c0, 1, __ATOMIC_RELAXED, __HIP_MEMORY_SCOPE_AGENT);
        if (p == 31) {
            int q = __hip_atomic_fetch_add(c1, 1, __ATOMIC_RELAXED, __HIP_MEMORY_SCOPE_AGENT);
            if (q == 7) {  // reset-before-release; vmcnt drain orders resets < gen
                for (int g = 0; g < 8; ++g)
                    __hip_atomic_store(bar + g * 32, 0, __ATOMIC_RELAXED,
                                       __HIP_MEMORY_SCOPE_AGENT);
                __hip_atomic_store(c1, 0, __ATOMIC_RELAXED, __HIP_MEMORY_SCOPE_AGENT);
                asm volatile("s_waitcnt vmcnt(0)" ::: "memory");
                __hip_atomic_store(gen, my + 1, __ATOMIC_RELAXED, __HIP_MEMORY_SCOPE_AGENT);
                rel = true;
            }
        }
        if (!rel) {
            long long t0 = clock64();
            int it = 0;
            while (__hip_atomic_load(gen, __ATOMIC_RELAXED, __HIP_MEMORY_SCOPE_AGENT) == my) {
                __builtin_amdgcn_s_sleep(1);
                if (((++it) & 255) == 0 && clock64() - t0 > 2000000000LL) break;  // escape
            }
        }
    }
    __syncthreads();
}

// ---- software-pipelined coherent K-loop: window of 4 chunk-pairs in flight.
// R2/R7 lesson: register budget is EXACTLY full (256 unified regs/lane at
// 8 waves/CU) -- no deeper window, no wider N. ks stride 1024 halves.
template <int KS, int MT>
struct KStep {
    static __device__ __forceinline__ void run(const _Float16* a0, const _Float16* a1,
                                               half8 (&b0)[4], half8 (&b1)[4],
                                               const half8 (&wf)[2][16],
                                               f32x16 (&acc)[MT][2]) {
        constexpr int slot = KS & 3;
        constexpr int CNT = MT * ((KS + 4 < 16) ? 3 : (15 - KS));
        if constexpr (MT == 2) vwait2<CNT>(b0[slot], b1[slot]);
        else vwait1<CNT>(b0[slot]);
        acc[0][0] = __builtin_amdgcn_mfma_f32_32x32x16_f16(b0[slot], wf[0][KS], acc[0][0], 0, 0, 0);
        acc[0][1] = __builtin_amdgcn_mfma_f32_32x32x16_f16(b0[slot], wf[1][KS], acc[0][1], 0, 0, 0);
        if constexpr (MT == 2) {
            acc[1][0] = __builtin_amdgcn_mfma_f32_32x32x16_f16(b1[slot], wf[0][KS], acc[1][0], 0, 0, 0);
            acc[1][1] = __builtin_amdgcn_mfma_f32_32x32x16_f16(b1[slot], wf[1][KS], acc[1][1], 0, 0, 0);
        }
        if constexpr (KS + 4 < 16) {
            b0[slot] = ldg_llc(a0 + (KS + 4) * 1024);
            if constexpr (MT == 2) b1[slot] = ldg_llc(a1 + (KS + 4) * 1024);
        }
        KStep<KS + 1, MT>::run(a0, a1, b0, b1, wf, acc);
    }
};
template <int MT>
struct KStep<16, MT> {
    static __device__ __forceinline__ void run(const _Float16*, const _Float16*, half8 (&)[4],
                                               half8 (&)[4], const half8 (&)[2][16],
                                               f32x16 (&)[MT][2]) {}
};

template <int MT>
__device__ __forceinline__ void cell_compute_coh(const _Float16* a0, const _Float16* a1,
                                                 const half8 (&wf)[2][16],
                                                 f32x16 (&acc)[MT][2]) {
#pragma unroll
    for (int mt = 0; mt < MT; ++mt)
#pragma unroll
        for (int nt = 0; nt < 2; ++nt)
#pragma unroll
            for (int r = 0; r < 16; ++r) acc[mt][nt][r] = 0.f;
    half8 b0[4], b1[4];
#pragma unroll
    for (int i = 0; i < 4; ++i) {
        b0[i] = ldg_llc(a0 + i * 1024);
        if constexpr (MT == 2) b1[i] = ldg_llc(a1 + i * 1024);
    }
    KStep<0, MT>::run(a0, a1, b0, b1, wf, acc);
}

// plain-cached path (layer-0 embedding reads, row-major ehi)
template <int MT>
__device__ __forceinline__ void cell_compute_plain(const _Float16* __restrict__ a0,
                                                   const _Float16* __restrict__ a1,
                                                   const half8 (&wf)[2][16],
                                                   f32x16 (&acc)[MT][2]) {
#pragma unroll
    for (int mt = 0; mt < MT; ++mt)
#pragma unroll
        for (int nt = 0; nt < 2; ++nt)
#pragma unroll
            for (int r = 0; r < 16; ++r) acc[mt][nt][r] = 0.f;
#pragma unroll
    for (int ks = 0; ks < 16; ++ks) {
        half8 x0 = *reinterpret_cast<const half8*>(a0 + ks * 16);
        acc[0][0] = __builtin_amdgcn_mfma_f32_32x32x16_f16(x0, wf[0][ks], acc[0][0], 0, 0, 0);
        acc[0][1] = __builtin_amdgcn_mfma_f32_32x32x16_f16(x0, wf[1][ks], acc[0][1], 0, 0, 0);
        if constexpr (MT == 2) {
            half8 x1 = *reinterpret_cast<const half8*>(a1 + ks * 16);
            acc[1][0] = __builtin_amdgcn_mfma_f32_32x32x16_f16(x1, wf[0][ks], acc[1][0], 0, 0, 0);
            acc[1][1] = __builtin_amdgcn_mfma_f32_32x32x16_f16(x1, wf[1][ks], acc[1][1], 0, 0, 0);
        }
    }
}

// part write: C layout (32x32): n=lane&31, m=4*(lane>>5)+(r&3)+8*(r>>2)
template <int MT, bool ADD>
__device__ __forceinline__ void part_write(float (*pw)[64], const f32x16 (&acc)[MT][2],
                                           int lane) {
    const int ln = lane & 31;
#pragma unroll
    for (int mt = 0; mt < MT; ++mt)
#pragma unroll
        for (int nt = 0; nt < 2; ++nt)
#pragma unroll
            for (int r = 0; r < 16; ++r) {
                int m = mt * 32 + 4 * (lane >> 5) + (r & 3) + 8 * (r >> 2);
                int n = nt * 32 + ln;
                int idx = n ^ ((m & 7) << 2);
                if (ADD) pw[m][idx] += acc[mt][nt][r];
                else pw[m][idx] = acc[mt][nt][r];
            }
}

// Persistent wavefront LSTM: 256 blocks x 512 threads (8 waves, 1 block/CU).
// Wave w: K-slice 256 (w<4: y/w_ih, w>=4: h/w_hh), full N=64.
__global__ __launch_bounds__(512, 2) void lstm_persistent(
    const int* __restrict__ padded_in, const int* __restrict__ in_lengths,
    const float* __restrict__ w_ih, const float* __restrict__ w_hh,
    const float* __restrict__ biasf, int* __restrict__ bar,
    const _Float16* __restrict__ ehi, _Float16* __restrict__ hbh,
    _Float16* __restrict__ ybh, float* __restrict__ out) {
    __shared__ __align__(16) float part[4][64][64];  // 64 KB

    const int cu = blockIdx.x;
    const int layer = cu >> 6;
    const int j0 = (cu & 63) * 16;
    const int tid = threadIdx.x;
    const int wv = tid >> 6;
    const int lane = tid & 63;
    const int ln = lane & 31;
    const int khalf = (lane >> 5) * 8;
    const bool isH = (wv >= 4);
    const int kb = (isH ? (wv - 4) : wv) * 256;

    // ---- one-time weight preload: fp32 -> fp16 frags, 128 VGPR/lane
    half8 wf[2][16];
    {
        const float* wsrc = isH ? w_hh : w_ih;
#pragma unroll
        for (int nt = 0; nt < 2; ++nt) {
            int n = nt * 32 + ln;
            const float* rowp =
                wsrc + ((size_t)layer * 4 * Hn + (n >> 4) * Hn + j0 + (n & 15)) * Hn + kb + khalf;
#pragma unroll
            for (int ks = 0; ks < 16; ++ks) {
                f32x4 a = *reinterpret_cast<const f32x4*>(rowp + ks * 16);
                f32x4 b = *reinterpret_cast<const f32x4*>(rowp + ks * 16 + 4);
                half8 h;
                h[0] = (_Float16)a[0]; h[1] = (_Float16)a[1];
                h[2] = (_Float16)a[2]; h[3] = (_Float16)a[3];
                h[4] = (_Float16)b[0]; h[5] = (_Float16)b[1];
                h[6] = (_Float16)b[2]; h[7] = (_Float16)b[3];
                wf[nt][ks] = h;
            }
        }
    }

    // epilogue ownership (threads 0..255): batch row brow, 4 units jcol..jcol+3
    const int brow = (tid & 255) >> 2;
    const int jcol = (tid & 3) * 4;
    const int J = j0 + jcol;
    const int po = perm_off(brow, J);  // loop-invariant permuted half-offset
    float bias[4][4];
#pragma unroll
    for (int g = 0; g < 4; ++g)
#pragma unroll
        for (int p = 0; p < 4; ++p)
            bias[g][p] = biasf[layer * 4096 + g * 1024 + J + p];

    float creg[4] = {0.f, 0.f, 0.f, 0.f};
    float hreg[4] = {0.f, 0.f, 0.f, 0.f};

    const bool carryOwner = (tid < 256) && (layer > 0) && (layer < 3);

    for (int w = 0; w < Sn + Ln - 1; ++w) {
        const int t = w - layer;
        if (t >= 0 && t < Sn) {
            const int bs = in_lengths[t];
            const int pin = t & 1;
            const int pout = pin ^ 1;

            // R8 exact row masking: rows >= bs produce DISCARDED gates (sorted
            // lengths -> active rows are a prefix). Redirect inactive lanes
            // (lane l <-> row l&31 in the permuted chunk) to the chunk's row 0;
            // redirected lanes coalesce onto already-fetched lines, so LLC
            // interface bytes ~ bs exactly.
            const int lim0 = bs < 32 ? bs : 32;
            const int lim1 = bs - 32;  // only consumed when MT==2 (bs>32)
            const int off0 = (ln < lim0) ? lane * 8 : (lane & 32) * 8;
            const int off1 = (ln < lim1) ? lane * 8 : (lane & 32) * 8;

            // early-issue inactive-row y-carry load (layers 1-2, inactive rows
            // only): pinned above the K-loop asm loads; latency hides under
            // compute; drained by the K-loop's terminal vmcnt(0) (KS=15: CNT=0).
            half4v ycarry{};
            if (carryOwner && brow >= bs)
                ycarry = ldg_llc4(&ybh[(size_t)(pin * 3 + layer - 1) * BH + po]);

            // per-wave A-source pointers for its K-slice (permuted layout:
            // chunk base + kb*64; ks stride 1024; chunk1 (rows 32-63) +512)
            const _Float16 *a0, *a1;
            bool coh;
            if (!isH) {
                if (layer == 0) {  // embedding: read-only, cacheable, row-major
                    const int ko = kb + khalf;
                    a0 = ehi + (size_t)padded_in[ln * Sn + t] * Hn + ko;
                    a1 = ehi + (size_t)padded_in[(32 + ln) * Sn + t] * Hn + ko;
                    coh = false;
                } else {
                    const _Float16* cb =
                        ybh + (size_t)(pin * 3 + layer - 1) * BH + (size_t)kb * 64;
                    a0 = cb + off0;
                    a1 = cb + 512 + off1;
                    coh = true;
                }
            } else {
                const _Float16* cb =
                    hbh + (size_t)(pin * Ln + layer) * BH + (size_t)kb * 64;
                a0 = cb + off0;
                a1 = cb + 512 + off1;
                coh = true;
            }

            // compute; two-phase partial accumulation (waves 0-3 store, 4-7 add)
            if (bs > 32) {
                f32x16 acc[2][2];
                if (coh) cell_compute_coh<2>(a0, a1, wf, acc);
                else cell_compute_plain<2>(a0, a1, wf, acc);
                if (wv < 4) part_write<2, false>(part[wv], acc, lane);
                __syncthreads();
                if (wv >= 4) part_write<2, true>(part[wv - 4], acc, lane);
            } else {
                f32x16 acc[1][2];
                if (coh) cell_compute_coh<1>(a0, a1, wf, acc);
                else cell_compute_plain<1>(a0, a1, wf, acc);
                if (wv < 4) part_write<1, false>(part[wv], acc, lane);
                __syncthreads();
                if (wv >= 4) part_write<1, true>(part[wv - 4], acc, lane);
            }
            __syncthreads();

            if (tid < 256) {
                // cross-wave K-reduction + bias
                float gsum[4][4];
#pragma unroll
                for (int g = 0; g < 4; ++g) {
                    int nidx = (g * 16 + jcol) ^ ((brow & 7) << 2);
                    f32x4 s = *reinterpret_cast<const f32x4*>(&part[0][brow][nidx]);
#pragma unroll
                    for (int p2 = 1; p2 < 4; ++p2)
                        s = s + *reinterpret_cast<const f32x4*>(&part[p2][brow][nidx]);
#pragma unroll
                    for (int p = 0; p < 4; ++p) gsum[g][p] = s[p] + bias[g][p];
                }

                const bool active = (brow < bs);
                float hold[4], ysum[4];
#pragma unroll
                for (int p = 0; p < 4; ++p) {
                    float cn = sigmf(gsum[1][p]) * creg[p] + sigmf(gsum[0][p]) * tanhf_(gsum[2][p]);
                    float hn = sigmf(gsum[3][p]) * tanhf_(cn);
                    hold[p] = hreg[p];
                    if (active) { creg[p] = cn; hreg[p] = hn; }
                    ysum[p] = hreg[p] + hold[p];
                }
                // R11: h broadcast only for ACTIVE rows. Inactive rows' h is
                // never read: lengths are non-increasing, so consumers at t+1
                // read only rows < bs(t+1) <= bs(t) (R8 redirect), and the
                // final output comes from hreg registers. Saves ~half the
                // h-store coherent traffic late in the sequence.
                if (active) {
                    half4v hh;
#pragma unroll
                    for (int p = 0; p < 4; ++p) hh[p] = (_Float16)hreg[p];
                    stg_coh4(&hbh[(size_t)(pout * Ln + layer) * BH + po], hh);
                }
                if (layer < 3) {  // y interface feed (same-parity slot, permuted) -> LLC
                    half4v yh;
                    if (active) {
#pragma unroll
                        for (int p = 0; p < 4; ++p) yh[p] = (_Float16)ysum[p];
                    } else {  // carry incoming y (x_t for l=0) verbatim
                        if (layer == 0) {
                            int ib = padded_in[brow * Sn + t];
                            yh = *reinterpret_cast<const half4v*>(&ehi[(size_t)ib * Hn + J]);
                        } else {
                            yh = ycarry;  // pre-issued at step start
                        }
                    }
                    stg_coh4(&ybh[(size_t)(pin * 3 + layer) * BH + po], yh);
                }
            }
        }
        grid_barrier(bar, cu);
    }

    if (layer == 3 && tid < 256) {
        f32x4 o;
#pragma unroll
        for (int p = 0; p < 4; ++p) o[p] = hreg[p];
        *reinterpret_cast<f32x4*>(&out[(size_t)brow * Hn + J]) = o;
    }
}

extern "C" void kernel_launch(void* const* d_in, const int* in_sizes, int n_in,
                              void* d_out, int out_size, void* d_ws, size_t ws_size,
                              hipStream_t stream) {
    const int* padded_in = (const int*)d_in[0];
    const int* in_lengths = (const int*)d_in[1];
    const float* emb = (const float*)d_in[2];
    const float* w_ih = (const float*)d_in[3];
    const float* w_hh = (const float*)d_in[4];
    const float* b_ih = (const float*)d_in[5];
    const float* b_hh = (const float*)d_in[6];
    float* outp = (float*)d_out;

    // workspace (~2 MB), all segments 16B-aligned
    char* w = (char*)d_ws;
    int* bar = (int*)w;            w += BAR_INTS * 4;
    float* biasf = (float*)w;      w += (size_t)Ln * 4 * Hn * 4;
    _Float16* ehi = (_Float16*)w;  w += (size_t)Vn * Hn * 2;
    _Float16* hbh = (_Float16*)w;  w += (size_t)2 * Ln * Bn * Hn * 2;
    _Float16* ybh = (_Float16*)w;  w += (size_t)2 * 3 * Bn * Hn * 2;

    init_kernel<<<256, 256, 0, stream>>>(b_ih, b_hh, emb, bar, biasf, ehi, hbh);
    lstm_persistent<<<NBLK, 512, 0, stream>>>(padded_in, in_lengths, w_ih, w_hh, biasf, bar,
                                              ehi, hbh, ybh, outp);
}

// Round 12
// 7212.637 us; speedup vs baseline: 2.3054x; 1.0229x over previous
//
#include <hip/hip_runtime.h>
#include <hip/hip_fp16.h>

// EncoderRNN: V=29, H=1024, L=4, B=64, S=512. Inputs/out are FLOAT32 (proven R1/R2).
#define Vn 29
#define Hn 1024
#define Ln 4
#define Bn 64
#define Sn 512
#define BH (Bn * Hn)
#define NBLK 256

typedef _Float16 half8 __attribute__((ext_vector_type(8)));
typedef _Float16 half4v __attribute__((ext_vector_type(4)));
typedef float f32x16 __attribute__((ext_vector_type(16)));
typedef float f32x4 __attribute__((ext_vector_type(4)));

__device__ __forceinline__ float sigmf(float x) { return 1.0f / (1.0f + __expf(-x)); }
__device__ __forceinline__ float tanhf_(float x) { return 1.0f - 2.0f / (__expf(2.0f * x) + 1.0f); }

// Wave-linear permuted layout for h/y interface buffers (we own both sides):
// element (row r, unit j) lives at half-offset
//   ((j>>4)*2 + (r>>5))*512 + (((j>>3)&1)*32 + (r&31))*8 + (j&7)
// K-loop wave-load of one MFMA A-chunk is CONTIGUOUS 1 KB (lane l reads
// base + l*16B; lane l <-> row l&31), full-line epilogue writes.
__device__ __forceinline__ int perm_off(int r, int j) {
    return (((j >> 4) * 2 + (r >> 5)) << 9) + ((((j >> 3) & 1) << 5) + (r & 31)) * 8 + (j & 7);
}

// --- LLC-coherent 16B load (bypass L1+L2, device coherence point). R6 lesson:
// cached loads + per-step agent fence = 2x SLOWER. sc0 sc1 direct is proven.
__device__ __forceinline__ half8 ldg_llc(const _Float16* p) {
    half8 v;
    asm volatile("global_load_dwordx4 %0, %1, off sc0 sc1" : "=v"(v) : "v"(p) : "memory");
    return v;
}
// 8B LLC-coherent load, asm-pinned issue point (hoisted y-carry load).
__device__ __forceinline__ half4v ldg_llc4(const _Float16* p) {
    half4v v;
    asm volatile("global_load_dwordx2 %0, %1, off sc0 sc1" : "=v"(v) : "v"(p) : "memory");
    return v;
}
// Wait until <=CNT vector-mem ops outstanding; ties operands so dependent MFMAs
// cannot be scheduled above the wait. Extra EARLIER VMEM ops are harmless:
// vmcnt retires in issue order.
template <int CNT>
__device__ __forceinline__ void vwait1(half8& a) {
    asm volatile("s_waitcnt vmcnt(%1)" : "+v"(a) : "i"(CNT));
}
template <int CNT>
__device__ __forceinline__ void vwait2(half8& a, half8& b) {
    asm volatile("s_waitcnt vmcnt(%2)" : "+v"(a), "+v"(b) : "i"(CNT));
}

__device__ __forceinline__ void stg_coh4(_Float16* p, half4v v) {
    union { half4v h; unsigned long long u; } c;
    c.h = v;
    __hip_atomic_store((unsigned long long*)p, c.u, __ATOMIC_RELAXED,
                       __HIP_MEMORY_SCOPE_AGENT);
}

// barrier block: c0[8] padded 32 ints apart (0..255), c1 at [256], gen at [288]
#define BAR_INTS 320

__global__ void init_kernel(const float* __restrict__ bi, const float* __restrict__ bh,
                            const float* __restrict__ emb, int* __restrict__ bar,
                            float* __restrict__ biasf, _Float16* __restrict__ ehi,
                            _Float16* __restrict__ hbh) {
    int i = blockIdx.x * blockDim.x + threadIdx.x;
    int stride = gridDim.x * blockDim.x;
    for (int k = i; k < BAR_INTS; k += stride) bar[k] = 0;
    for (int k = i; k < Ln * 4 * Hn; k += stride) biasf[k] = bi[k] + bh[k];
    for (int k = i; k < Vn * Hn; k += stride)
        ehi[k] = (_Float16)((k < Hn) ? 0.f : emb[k]);  // padding_idx=0 row zero
    for (int k = i; k < 2 * Ln * Bn * Hn; k += stride) hbh[k] = (_Float16)0.f;
}

// Grid barrier, R12: PROVEN atomic-tree shape (R2/R3/R8/R11 pass; do NOT
// change the protocol structure -- R9/R10's flag-array redesign faulted
// twice), with two critical-path trims that keep the shape intact:
//  (a) my = step-1 is DETERMINISTIC (gen increments exactly once per barrier)
//      -> the serialized gen pre-load RT is replaced by a constant.
//  (b) MONOTONIC counters: last-in-group is p == 32*step-1, releaser is
//      q == 8*step-1, gen := step. No reset phase, no reset-drain -> the
//      release store issues immediately after the c1 RMW returns.
// Max counter value 32*515 = 16480: no overflow. Escape timeouts kept.
__device__ __forceinline__ void grid_barrier(int* __restrict__ bar, int bid, int step) {
    asm volatile("s_waitcnt vmcnt(0)" ::: "memory");  // drain this wave's stores
    __syncthreads();
    if (threadIdx.x == 0) {
        int* c0 = bar + (bid & 7) * 32;
        int* c1 = bar + 256;
        int* gen = bar + 288;
        bool rel = false;
        int p = __hip_atomic_fetch_add(c0, 1, __ATOMIC_RELAXED, __HIP_MEMORY_SCOPE_AGENT);
        if (p == 32 * step - 1) {  // group's last arrival for this step
            int q = __hip_atomic_fetch_add(c1, 1, __ATOMIC_RELAXED, __HIP_MEMORY_SCOPE_AGENT);
            if (q == 8 * step - 1) {  // grid's last group
                __hip_atomic_store(gen, step, __ATOMIC_RELAXED, __HIP_MEMORY_SCOPE_AGENT);
                rel = true;
            }
        }
        if (!rel) {
            long long t0 = clock64();
            int it = 0;
            while (__hip_atomic_load(gen, __ATOMIC_RELAXED, __HIP_MEMORY_SCOPE_AGENT) < step) {
                __builtin_amdgcn_s_sleep(1);
                if (((++it) & 255) == 0 && clock64() - t0 > 2000000000LL) break;  // escape
            }
        }
    }
    __syncthreads();
}

// ---- software-pipelined coherent K-loop: window of 4 chunk-pairs in flight.
// R2/R7 lesson: register budget is EXACTLY full (128 VGPR cap at 2 waves/SIMD;
// wf alone = 128) -- no deeper window, no wider N. ks stride 1024 halves.
template <int KS, int MT>
struct KStep {
    static __device__ __forceinline__ void run(const _Float16* a0, const _Float16* a1,
                                               half8 (&b0)[4], half8 (&b1)[4],
                                               const half8 (&wf)[2][16],
                                               f32x16 (&acc)[MT][2]) {
        constexpr int slot = KS & 3;
        constexpr int CNT = MT * ((KS + 4 < 16) ? 3 : (15 - KS));
        if constexpr (MT == 2) vwait2<CNT>(b0[slot], b1[slot]);
        else vwait1<CNT>(b0[slot]);
        acc[0][0] = __builtin_amdgcn_mfma_f32_32x32x16_f16(b0[slot], wf[0][KS], acc[0][0], 0, 0, 0);
        acc[0][1] = __builtin_amdgcn_mfma_f32_32x32x16_f16(b0[slot], wf[1][KS], acc[0][1], 0, 0, 0);
        if constexpr (MT == 2) {
            acc[1][0] = __builtin_amdgcn_mfma_f32_32x32x16_f16(b1[slot], wf[0][KS], acc[1][0], 0, 0, 0);
            acc[1][1] = __builtin_amdgcn_mfma_f32_32x32x16_f16(b1[slot], wf[1][KS], acc[1][1], 0, 0, 0);
        }
        if constexpr (KS + 4 < 16) {
            b0[slot] = ldg_llc(a0 + (KS + 4) * 1024);
            if constexpr (MT == 2) b1[slot] = ldg_llc(a1 + (KS + 4) * 1024);
        }
        KStep<KS + 1, MT>::run(a0, a1, b0, b1, wf, acc);
    }
};
template <int MT>
struct KStep<16, MT> {
    static __device__ __forceinline__ void run(const _Float16*, const _Float16*, half8 (&)[4],
                                               half8 (&)[4], const half8 (&)[2][16],
                                               f32x16 (&)[MT][2]) {}
};

template <int MT>
__device__ __forceinline__ void cell_compute_coh(const _Float16* a0, const _Float16* a1,
                                                 const half8 (&wf)[2][16],
                                                 f32x16 (&acc)[MT][2]) {
#pragma unroll
    for (int mt = 0; mt < MT; ++mt)
#pragma unroll
        for (int nt = 0; nt < 2; ++nt)
#pragma unroll
            for (int r = 0; r < 16; ++r) acc[mt][nt][r] = 0.f;
    half8 b0[4], b1[4];
#pragma unroll
    for (int i = 0; i < 4; ++i) {
        b0[i] = ldg_llc(a0 + i * 1024);
        if constexpr (MT == 2) b1[i] = ldg_llc(a1 + i * 1024);
    }
    KStep<0, MT>::run(a0, a1, b0, b1, wf, acc);
}

// plain-cached path (layer-0 embedding reads, row-major ehi)
template <int MT>
__device__ __forceinline__ void cell_compute_plain(const _Float16* __restrict__ a0,
                                                   const _Float16* __restrict__ a1,
                                                   const half8 (&wf)[2][16],
                                                   f32x16 (&acc)[MT][2]) {
#pragma unroll
    for (int mt = 0; mt < MT; ++mt)
#pragma unroll
        for (int nt = 0; nt < 2; ++nt)
#pragma unroll
            for (int r = 0; r < 16; ++r) acc[mt][nt][r] = 0.f;
#pragma unroll
    for (int ks = 0; ks < 16; ++ks) {
        half8 x0 = *reinterpret_cast<const half8*>(a0 + ks * 16);
        acc[0][0] = __builtin_amdgcn_mfma_f32_32x32x16_f16(x0, wf[0][ks], acc[0][0], 0, 0, 0);
        acc[0][1] = __builtin_amdgcn_mfma_f32_32x32x16_f16(x0, wf[1][ks], acc[0][1], 0, 0, 0);
        if constexpr (MT == 2) {
            half8 x1 = *reinterpret_cast<const half8*>(a1 + ks * 16);
            acc[1][0] = __builtin_amdgcn_mfma_f32_32x32x16_f16(x1, wf[0][ks], acc[1][0], 0, 0, 0);
            acc[1][1] = __builtin_amdgcn_mfma_f32_32x32x16_f16(x1, wf[1][ks], acc[1][1], 0, 0, 0);
        }
    }
}

// part write: C layout (32x32): n=lane&31, m=4*(lane>>5)+(r&3)+8*(r>>2)
template <int MT, bool ADD>
__device__ __forceinline__ void part_write(float (*pw)[64], const f32x16 (&acc)[MT][2],
                                           int lane) {
    const int ln = lane & 31;
#pragma unroll
    for (int mt = 0; mt < MT; ++mt)
#pragma unroll
        for (int nt = 0; nt < 2; ++nt)
#pragma unroll
            for (int r = 0; r < 16; ++r) {
                int m = mt * 32 + 4 * (lane >> 5) + (r & 3) + 8 * (r >> 2);
                int n = nt * 32 + ln;
                int idx = n ^ ((m & 7) << 2);
                if (ADD) pw[m][idx] += acc[mt][nt][r];
                else pw[m][idx] = acc[mt][nt][r];
            }
}

// Persistent wavefront LSTM: 256 blocks x 512 threads (8 waves, 1 block/CU).
// Wave w: K-slice 256 (w<4: y/w_ih, w>=4: h/w_hh), full N=64.
__global__ __launch_bounds__(512, 2) void lstm_persistent(
    const int* __restrict__ padded_in, const int* __restrict__ in_lengths,
    const float* __restrict__ w_ih, const float* __restrict__ w_hh,
    const float* __restrict__ biasf, int* __restrict__ bar,
    const _Float16* __restrict__ ehi, _Float16* __restrict__ hbh,
    _Float16* __restrict__ ybh, float* __restrict__ out) {
    __shared__ __align__(16) float part[4][64][64];  // 64 KB

    const int cu = blockIdx.x;
    const int layer = cu >> 6;
    const int j0 = (cu & 63) * 16;
    const int tid = threadIdx.x;
    const int wv = tid >> 6;
    const int lane = tid & 63;
    const int ln = lane & 31;
    const int khalf = (lane >> 5) * 8;
    const bool isH = (wv >= 4);
    const int kb = (isH ? (wv - 4) : wv) * 256;

    // ---- one-time weight preload: fp32 -> fp16 frags, 128 VGPR/lane
    half8 wf[2][16];
    {
        const float* wsrc = isH ? w_hh : w_ih;
#pragma unroll
        for (int nt = 0; nt < 2; ++nt) {
            int n = nt * 32 + ln;
            const float* rowp =
                wsrc + ((size_t)layer * 4 * Hn + (n >> 4) * Hn + j0 + (n & 15)) * Hn + kb + khalf;
#pragma unroll
            for (int ks = 0; ks < 16; ++ks) {
                f32x4 a = *reinterpret_cast<const f32x4*>(rowp + ks * 16);
                f32x4 b = *reinterpret_cast<const f32x4*>(rowp + ks * 16 + 4);
                half8 h;
                h[0] = (_Float16)a[0]; h[1] = (_Float16)a[1];
                h[2] = (_Float16)a[2]; h[3] = (_Float16)a[3];
                h[4] = (_Float16)b[0]; h[5] = (_Float16)b[1];
                h[6] = (_Float16)b[2]; h[7] = (_Float16)b[3];
                wf[nt][ks] = h;
            }
        }
    }

    // epilogue ownership (threads 0..255): batch row brow, 4 units jcol..jcol+3
    const int brow = (tid & 255) >> 2;
    const int jcol = (tid & 3) * 4;
    const int J = j0 + jcol;
    const int po = perm_off(brow, J);  // loop-invariant permuted half-offset
    float bias[4][4];
#pragma unroll
    for (int g = 0; g < 4; ++g)
#pragma unroll
        for (int p = 0; p < 4; ++p)
            bias[g][p] = biasf[layer * 4096 + g * 1024 + J + p];

    float creg[4] = {0.f, 0.f, 0.f, 0.f};
    float hreg[4] = {0.f, 0.f, 0.f, 0.f};

    const bool carryOwner = (tid < 256) && (layer > 0) && (layer < 3);

    for (int w = 0; w < Sn + Ln - 1; ++w) {
        const int t = w - layer;
        if (t >= 0 && t < Sn) {
            const int bs = in_lengths[t];
            const int pin = t & 1;
            const int pout = pin ^ 1;

            // R8 exact row masking: rows >= bs produce DISCARDED gates (sorted
            // lengths -> active rows are a prefix). Redirect inactive lanes
            // (lane l <-> row l&31 in the permuted chunk) to the chunk's row 0;
            // redirected lanes coalesce onto already-fetched lines, so LLC
            // interface bytes ~ bs exactly.
            const int lim0 = bs < 32 ? bs : 32;
            const int lim1 = bs - 32;  // only consumed when MT==2 (bs>32)
            const int off0 = (ln < lim0) ? lane * 8 : (lane & 32) * 8;
            const int off1 = (ln < lim1) ? lane * 8 : (lane & 32) * 8;

            // early-issue inactive-row y-carry load (layers 1-2, inactive rows
            // only): pinned above the K-loop asm loads; latency hides under
            // compute; drained by the K-loop's terminal vmcnt(0) (KS=15: CNT=0).
            half4v ycarry{};
            if (carryOwner && brow >= bs)
                ycarry = ldg_llc4(&ybh[(size_t)(pin * 3 + layer - 1) * BH + po]);

            // per-wave A-source pointers for its K-slice (permuted layout:
            // chunk base + kb*64; ks stride 1024; chunk1 (rows 32-63) +512)
            const _Float16 *a0, *a1;
            bool coh;
            if (!isH) {
                if (layer == 0) {  // embedding: read-only, cacheable, row-major
                    const int ko = kb + khalf;
                    a0 = ehi + (size_t)padded_in[ln * Sn + t] * Hn + ko;
                    a1 = ehi + (size_t)padded_in[(32 + ln) * Sn + t] * Hn + ko;
                    coh = false;
                } else {
                    const _Float16* cb =
                        ybh + (size_t)(pin * 3 + layer - 1) * BH + (size_t)kb * 64;
                    a0 = cb + off0;
                    a1 = cb + 512 + off1;
                    coh = true;
                }
            } else {
                const _Float16* cb =
                    hbh + (size_t)(pin * Ln + layer) * BH + (size_t)kb * 64;
                a0 = cb + off0;
                a1 = cb + 512 + off1;
                coh = true;
            }

            // compute; two-phase partial accumulation (waves 0-3 store, 4-7 add)
            if (bs > 32) {
                f32x16 acc[2][2];
                if (coh) cell_compute_coh<2>(a0, a1, wf, acc);
                else cell_compute_plain<2>(a0, a1, wf, acc);
                if (wv < 4) part_write<2, false>(part[wv], acc, lane);
                __syncthreads();
                if (wv >= 4) part_write<2, true>(part[wv - 4], acc, lane);
            } else {
                f32x16 acc[1][2];
                if (coh) cell_compute_coh<1>(a0, a1, wf, acc);
                else cell_compute_plain<1>(a0, a1, wf, acc);
                if (wv < 4) part_write<1, false>(part[wv], acc, lane);
                __syncthreads();
                if (wv >= 4) part_write<1, true>(part[wv - 4], acc, lane);
            }
            __syncthreads();

            if (tid < 256) {
                // cross-wave K-reduction + bias
                float gsum[4][4];
#pragma unroll
                for (int g = 0; g < 4; ++g) {
                    int nidx = (g * 16 + jcol) ^ ((brow & 7) << 2);
                    f32x4 s = *reinterpret_cast<const f32x4*>(&part[0][brow][nidx]);
#pragma unroll
                    for (int p2 = 1; p2 < 4; ++p2)
                        s = s + *reinterpret_cast<const f32x4*>(&part[p2][brow][nidx]);
#pragma unroll
                    for (int p = 0; p < 4; ++p) gsum[g][p] = s[p] + bias[g][p];
                }

                const bool active = (brow < bs);
                float hold[4], ysum[4];
#pragma unroll
                for (int p = 0; p < 4; ++p) {
                    float cn = sigmf(gsum[1][p]) * creg[p] + sigmf(gsum[0][p]) * tanhf_(gsum[2][p]);
                    float hn = sigmf(gsum[3][p]) * tanhf_(cn);
                    hold[p] = hreg[p];
                    if (active) { creg[p] = cn; hreg[p] = hn; }
                    ysum[p] = hreg[p] + hold[p];
                }
                // R11: h broadcast only for ACTIVE rows. Inactive rows' h is
                // never read (non-increasing lengths + R8 redirect; final
                // output comes from hreg registers).
                if (active) {
                    half4v hh;
#pragma unroll
                    for (int p = 0; p < 4; ++p) hh[p] = (_Float16)hreg[p];
                    stg_coh4(&hbh[(size_t)(pout * Ln + layer) * BH + po], hh);
                }
                if (layer < 3) {  // y interface feed (same-parity slot, permuted) -> LLC
                    half4v yh;
                    if (active) {
#pragma unroll
                        for (int p = 0; p < 4; ++p) yh[p] = (_Float16)ysum[p];
                    } else {  // carry incoming y (x_t for l=0) verbatim
                        if (layer == 0) {
                            int ib = padded_in[brow * Sn + t];
                            yh = *reinterpret_cast<const half4v*>(&ehi[(size_t)ib * Hn + J]);
                        } else {
                            yh = ycarry;  // pre-issued at step start
                        }
                    }
                    stg_coh4(&ybh[(size_t)(pin * 3 + layer) * BH + po], yh);
                }
            }
        }
        grid_barrier(bar, cu, w + 1);
    }

    if (layer == 3 && tid < 256) {
        f32x4 o;
#pragma unroll
        for (int p = 0; p < 4; ++p) o[p] = hreg[p];
        *reinterpret_cast<f32x4*>(&out[(size_t)brow * Hn + J]) = o;
    }
}

extern "C" void kernel_launch(void* const* d_in, const int* in_sizes, int n_in,
                              void* d_out, int out_size, void* d_ws, size_t ws_size,
                              hipStream_t stream) {
    const int* padded_in = (const int*)d_in[0];
    const int* in_lengths = (const int*)d_in[1];
    const float* emb = (const float*)d_in[2];
    const float* w_ih = (const float*)d_in[3];
    const float* w_hh = (const float*)d_in[4];
    const float* b_ih = (const float*)d_in[5];
    const float* b_hh = (const float*)d_in[6];
    float* outp = (float*)d_out;

    // workspace (~2 MB), all segments 16B-aligned
    char* w = (char*)d_ws;
    int* bar = (int*)w;            w += BAR_INTS * 4;
    float* biasf = (float*)w;      w += (size_t)Ln * 4 * Hn * 4;
    _Float16* ehi = (_Float16*)w;  w += (size_t)Vn * Hn * 2;
    _Float16* hbh = (_Float16*)w;  w += (size_t)2 * Ln * Bn * Hn * 2;
    _Float16* ybh = (_Float16*)w;  w += (size_t)2 * 3 * Bn * Hn * 2;

    init_kernel<<<256, 256, 0, stream>>>(b_ih, b_hh, emb, bar, biasf, ehi, hbh);
    lstm_persistent<<<NBLK, 512, 0, stream>>>(padded_in, in_lengths, w_ih, w_hh, biasf, bar,
                                              ehi, hbh, ybh, outp);
}

// Round 13
// 6151.967 us; speedup vs baseline: 2.7029x; 1.1724x over previous
//
#include <hip/hip_runtime.h>
#include <hip/hip_fp16.h>

// EncoderRNN: V=29, H=1024, L=4, B=64, S=512. Inputs/out are FLOAT32 (proven R1/R2).
#define Vn 29
#define Hn 1024
#define Ln 4
#define Bn 64
#define Sn 512
#define BH (Bn * Hn)
#define NBLK 256

typedef _Float16 half8 __attribute__((ext_vector_type(8)));
typedef _Float16 half4v __attribute__((ext_vector_type(4)));
typedef float f32x16 __attribute__((ext_vector_type(16)));
typedef float f32x4 __attribute__((ext_vector_type(4)));

__device__ __forceinline__ float sigmf(float x) { return 1.0f / (1.0f + __expf(-x)); }
__device__ __forceinline__ float tanhf_(float x) { return 1.0f - 2.0f / (__expf(2.0f * x) + 1.0f); }

// Wave-linear permuted layout for h/y interface buffers (we own both sides):
// element (row r, unit j) lives at half-offset
//   ((j>>4)*2 + (r>>5))*512 + (((j>>3)&1)*32 + (r&31))*8 + (j&7)
// K-loop wave-load of one MFMA A-chunk is CONTIGUOUS 1 KB (lane l reads
// base + l*16B; lane l <-> row l&31), full-line epilogue writes. This ALSO
// matches global_load_lds's write pattern (wave-uniform LDS base + lane*16B).
__device__ __forceinline__ int perm_off(int r, int j) {
    return (((j >> 4) * 2 + (r >> 5)) << 9) + ((((j >> 3) & 1) << 5) + (r & 31)) * 8 + (j & 7);
}

// 8B LLC-coherent load, asm-pinned issue point (hoisted y-carry load).
__device__ __forceinline__ half4v ldg_llc4(const _Float16* p) {
    half4v v;
    asm volatile("global_load_dwordx2 %0, %1, off sc0 sc1" : "=v"(v) : "v"(p) : "memory");
    return v;
}

// R13: async global->LDS staging, LLC-coherent. aux=17 = sc0|sc1 (CPol GLC=1 +
// SCC=16 on gfx94x+) -- same coherence semantics as the proven ldg_llc path.
// Global src is per-lane; LDS dst is wave-uniform base + lane*16 (HW rule),
// which our permuted layout matches exactly. Zero VGPR cost per in-flight load
// -> pipeline depth 8 (register window was capped at 4 since R2).
__device__ __forceinline__ void gld_lds16(const _Float16* g, _Float16* l) {
    __builtin_amdgcn_global_load_lds(
        (const __attribute__((address_space(1))) void*)g,
        (__attribute__((address_space(3))) void*)l, 16, 0, 17);
}

__device__ __forceinline__ void stg_coh4(_Float16* p, half4v v) {
    union { half4v h; unsigned long long u; } c;
    c.h = v;
    __hip_atomic_store((unsigned long long*)p, c.u, __ATOMIC_RELAXED,
                       __HIP_MEMORY_SCOPE_AGENT);
}

// barrier block: c0[8] padded 32 ints apart (0..255), c1 at [256], gen at [288]
#define BAR_INTS 320

__global__ void init_kernel(const float* __restrict__ bi, const float* __restrict__ bh,
                            const float* __restrict__ emb, int* __restrict__ bar,
                            float* __restrict__ biasf, _Float16* __restrict__ ehi,
                            _Float16* __restrict__ hbh) {
    int i = blockIdx.x * blockDim.x + threadIdx.x;
    int stride = gridDim.x * blockDim.x;
    for (int k = i; k < BAR_INTS; k += stride) bar[k] = 0;
    for (int k = i; k < Ln * 4 * Hn; k += stride) biasf[k] = bi[k] + bh[k];
    for (int k = i; k < Vn * Hn; k += stride)
        ehi[k] = (_Float16)((k < Hn) ? 0.f : emb[k]);  // padding_idx=0 row zero
    for (int k = i; k < 2 * Ln * Bn * Hn; k += stride) hbh[k] = (_Float16)0.f;
}

// Grid barrier, R12-proven: atomic-tree shape with deterministic-step
// monotonic counters (no gen pre-load, no reset phase). Do NOT change the
// protocol structure (R9/R10 flag-array redesign faulted twice).
__device__ __forceinline__ void grid_barrier(int* __restrict__ bar, int bid, int step) {
    asm volatile("s_waitcnt vmcnt(0)" ::: "memory");  // drain this wave's stores
    __syncthreads();
    if (threadIdx.x == 0) {
        int* c0 = bar + (bid & 7) * 32;
        int* c1 = bar + 256;
        int* gen = bar + 288;
        bool rel = false;
        int p = __hip_atomic_fetch_add(c0, 1, __ATOMIC_RELAXED, __HIP_MEMORY_SCOPE_AGENT);
        if (p == 32 * step - 1) {  // group's last arrival for this step
            int q = __hip_atomic_fetch_add(c1, 1, __ATOMIC_RELAXED, __HIP_MEMORY_SCOPE_AGENT);
            if (q == 8 * step - 1) {  // grid's last group
                __hip_atomic_store(gen, step, __ATOMIC_RELAXED, __HIP_MEMORY_SCOPE_AGENT);
                rel = true;
            }
        }
        if (!rel) {
            long long t0 = clock64();
            int it = 0;
            while (__hip_atomic_load(gen, __ATOMIC_RELAXED, __HIP_MEMORY_SCOPE_AGENT) < step) {
                __builtin_amdgcn_s_sleep(1);
                if (((++it) & 255) == 0 && clock64() - t0 > 2000000000LL) break;  // escape
            }
        }
    }
    __syncthreads();
}

// ---- R13 K-loop: 8-deep global->LDS pipeline + 2-slot LDS->reg read-ahead.
// Per iter KS: vmcnt-wait slot KS+1 arrived in LDS ("memory" clobber pins the
// following ds_read) -> ds_read slot KS+1 into reg[(KS+1)&1] (compiler inserts
// precise lgkmcnt before the MFMAs) -> 4 MFMA on reg[KS&1] -> issue
// global_load_lds for slot KS+8 into phys slot KS&7 (safe: the lgkmcnt before
// this iter's MFMAs guarantees the ds_read of that phys slot retired).
// vmcnt budget: issued slots <= KS+7; want KS+1 arrived -> CNT = MT*min(6,14-KS).
// Terminal KS=14 gives vmcnt(0), which also drains the early ycarry load.
template <int KS, int MT>
struct KStepL {
    static __device__ __forceinline__ void run(const _Float16* a0, const _Float16* a1,
                                               _Float16* s0, _Float16* s1, int lane,
                                               half8 (&x0)[2], half8 (&x1)[2],
                                               const half8 (&wf)[2][16],
                                               f32x16 (&acc)[MT][2]) {
        if constexpr (KS < 15) {
            constexpr int CNT = MT * ((14 - KS) < 6 ? (14 - KS) : 6);
            asm volatile("s_waitcnt vmcnt(%0)" :: "i"(CNT) : "memory");
            x0[(KS + 1) & 1] =
                *reinterpret_cast<const half8*>(s0 + ((KS + 1) & 7) * 512 + lane * 8);
            if constexpr (MT == 2)
                x1[(KS + 1) & 1] =
                    *reinterpret_cast<const half8*>(s1 + ((KS + 1) & 7) * 512 + lane * 8);
        }
        acc[0][0] = __builtin_amdgcn_mfma_f32_32x32x16_f16(x0[KS & 1], wf[0][KS], acc[0][0], 0, 0, 0);
        acc[0][1] = __builtin_amdgcn_mfma_f32_32x32x16_f16(x0[KS & 1], wf[1][KS], acc[0][1], 0, 0, 0);
        if constexpr (MT == 2) {
            acc[1][0] = __builtin_amdgcn_mfma_f32_32x32x16_f16(x1[KS & 1], wf[0][KS], acc[1][0], 0, 0, 0);
            acc[1][1] = __builtin_amdgcn_mfma_f32_32x32x16_f16(x1[KS & 1], wf[1][KS], acc[1][1], 0, 0, 0);
        }
        if constexpr (KS + 8 < 16) {
            gld_lds16(a0 + (KS + 8) * 1024, s0 + (KS & 7) * 512);
            if constexpr (MT == 2) gld_lds16(a1 + (KS + 8) * 1024, s1 + (KS & 7) * 512);
        }
        KStepL<KS + 1, MT>::run(a0, a1, s0, s1, lane, x0, x1, wf, acc);
    }
};
template <int MT>
struct KStepL<16, MT> {
    static __device__ __forceinline__ void run(const _Float16*, const _Float16*, _Float16*,
                                               _Float16*, int, half8 (&)[2], half8 (&)[2],
                                               const half8 (&)[2][16], f32x16 (&)[MT][2]) {}
};

template <int MT>
__device__ __forceinline__ void cell_compute_lds(const _Float16* a0, const _Float16* a1,
                                                 _Float16* s0, _Float16* s1, int lane,
                                                 const half8 (&wf)[2][16],
                                                 f32x16 (&acc)[MT][2]) {
#pragma unroll
    for (int mt = 0; mt < MT; ++mt)
#pragma unroll
        for (int nt = 0; nt < 2; ++nt)
#pragma unroll
            for (int r = 0; r < 16; ++r) acc[mt][nt][r] = 0.f;
    // prologue: fill all 8 slots, wait slot 0, prime reg window
#pragma unroll
    for (int i = 0; i < 8; ++i) {
        gld_lds16(a0 + i * 1024, s0 + i * 512);
        if constexpr (MT == 2) gld_lds16(a1 + i * 1024, s1 + i * 512);
    }
    asm volatile("s_waitcnt vmcnt(%0)" :: "i"(MT * 7) : "memory");
    half8 x0[2], x1[2];
    x0[0] = *reinterpret_cast<const half8*>(s0 + lane * 8);
    if constexpr (MT == 2) x1[0] = *reinterpret_cast<const half8*>(s1 + lane * 8);
    KStepL<0, MT>::run(a0, a1, s0, s1, lane, x0, x1, wf, acc);
}

// plain-cached path (layer-0 embedding reads, row-major ehi)
template <int MT>
__device__ __forceinline__ void cell_compute_plain(const _Float16* __restrict__ a0,
                                                   const _Float16* __restrict__ a1,
                                                   const half8 (&wf)[2][16],
                                                   f32x16 (&acc)[MT][2]) {
#pragma unroll
    for (int mt = 0; mt < MT; ++mt)
#pragma unroll
        for (int nt = 0; nt < 2; ++nt)
#pragma unroll
            for (int r = 0; r < 16; ++r) acc[mt][nt][r] = 0.f;
#pragma unroll
    for (int ks = 0; ks < 16; ++ks) {
        half8 x0 = *reinterpret_cast<const half8*>(a0 + ks * 16);
        acc[0][0] = __builtin_amdgcn_mfma_f32_32x32x16_f16(x0, wf[0][ks], acc[0][0], 0, 0, 0);
        acc[0][1] = __builtin_amdgcn_mfma_f32_32x32x16_f16(x0, wf[1][ks], acc[0][1], 0, 0, 0);
        if constexpr (MT == 2) {
            half8 x1 = *reinterpret_cast<const half8*>(a1 + ks * 16);
            acc[1][0] = __builtin_amdgcn_mfma_f32_32x32x16_f16(x1, wf[0][ks], acc[1][0], 0, 0, 0);
            acc[1][1] = __builtin_amdgcn_mfma_f32_32x32x16_f16(x1, wf[1][ks], acc[1][1], 0, 0, 0);
        }
    }
}

// part write: C layout (32x32): n=lane&31, m=4*(lane>>5)+(r&3)+8*(r>>2)
template <int MT, bool ADD>
__device__ __forceinline__ void part_write(float (*pw)[64], const f32x16 (&acc)[MT][2],
                                           int lane) {
    const int ln = lane & 31;
#pragma unroll
    for (int mt = 0; mt < MT; ++mt)
#pragma unroll
        for (int nt = 0; nt < 2; ++nt)
#pragma unroll
            for (int r = 0; r < 16; ++r) {
                int m = mt * 32 + 4 * (lane >> 5) + (r & 3) + 8 * (r >> 2);
                int n = nt * 32 + ln;
                int idx = n ^ ((m & 7) << 2);
                if (ADD) pw[m][idx] += acc[mt][nt][r];
                else pw[m][idx] = acc[mt][nt][r];
            }
}

// Persistent wavefront LSTM: 256 blocks x 512 threads (8 waves, 1 block/CU).
// Wave w: K-slice 256 (w<4: y/w_ih, w>=4: h/w_hh), full N=64.
// LDS 128KB: stage[wave][chain][slot] 8x2x8x1KB. part[4][64][64] (64KB)
// aliases waves 0-3's stage EXACTLY (part[wv] == wave wv's own 16KB region),
// so same-wave program order makes the alias race-free (no extra syncs).
__global__ __launch_bounds__(512, 2) void lstm_persistent(
    const int* __restrict__ padded_in, const int* __restrict__ in_lengths,
    const float* __restrict__ w_ih, const float* __restrict__ w_hh,
    const float* __restrict__ biasf, int* __restrict__ bar,
    const _Float16* __restrict__ ehi, _Float16* __restrict__ hbh,
    _Float16* __restrict__ ybh, float* __restrict__ out) {
    __shared__ __align__(1024) char ldsbuf[131072];
    float (*part)[64][64] = reinterpret_cast<float (*)[64][64]>(ldsbuf);

    const int cu = blockIdx.x;
    const int layer = cu >> 6;
    const int j0 = (cu & 63) * 16;
    const int tid = threadIdx.x;
    const int wv = tid >> 6;
    const int lane = tid & 63;
    const int ln = lane & 31;
    const int khalf = (lane >> 5) * 8;
    const bool isH = (wv >= 4);
    const int kb = (isH ? (wv - 4) : wv) * 256;

    // this wave's LDS stage bases (halves): 8192 halves/wave, chain stride 4096
    _Float16* s0 = reinterpret_cast<_Float16*>(ldsbuf) + wv * 8192;
    _Float16* s1 = s0 + 4096;

    // ---- one-time weight preload: fp32 -> fp16 frags, 128 regs/lane
    half8 wf[2][16];
    {
        const float* wsrc = isH ? w_hh : w_ih;
#pragma unroll
        for (int nt = 0; nt < 2; ++nt) {
            int n = nt * 32 + ln;
            const float* rowp =
                wsrc + ((size_t)layer * 4 * Hn + (n >> 4) * Hn + j0 + (n & 15)) * Hn + kb + khalf;
#pragma unroll
            for (int ks = 0; ks < 16; ++ks) {
                f32x4 a = *reinterpret_cast<const f32x4*>(rowp + ks * 16);
                f32x4 b = *reinterpret_cast<const f32x4*>(rowp + ks * 16 + 4);
                half8 h;
                h[0] = (_Float16)a[0]; h[1] = (_Float16)a[1];
                h[2] = (_Float16)a[2]; h[3] = (_Float16)a[3];
                h[4] = (_Float16)b[0]; h[5] = (_Float16)b[1];
                h[6] = (_Float16)b[2]; h[7] = (_Float16)b[3];
                wf[nt][ks] = h;
            }
        }
    }

    // epilogue ownership (threads 0..255): batch row brow, 4 units jcol..jcol+3
    const int brow = (tid & 255) >> 2;
    const int jcol = (tid & 3) * 4;
    const int J = j0 + jcol;
    const int po = perm_off(brow, J);  // loop-invariant permuted half-offset
    float bias[4][4];
#pragma unroll
    for (int g = 0; g < 4; ++g)
#pragma unroll
        for (int p = 0; p < 4; ++p)
            bias[g][p] = biasf[layer * 4096 + g * 1024 + J + p];

    float creg[4] = {0.f, 0.f, 0.f, 0.f};
    float hreg[4] = {0.f, 0.f, 0.f, 0.f};

    const bool carryOwner = (tid < 256) && (layer > 0) && (layer < 3);

    for (int w = 0; w < Sn + Ln - 1; ++w) {
        const int t = w - layer;
        if (t >= 0 && t < Sn) {
            const int bs = in_lengths[t];
            const int pin = t & 1;
            const int pout = pin ^ 1;

            // R8 exact row masking: rows >= bs produce DISCARDED gates (sorted
            // lengths -> active rows are a prefix). Redirect inactive lanes
            // (lane l <-> row l&31 in the permuted chunk) to the chunk's row 0;
            // redirected lanes coalesce onto already-fetched lines, so LLC
            // interface bytes ~ bs exactly.
            const int lim0 = bs < 32 ? bs : 32;
            const int lim1 = bs - 32;  // only consumed when MT==2 (bs>32)
            const int off0 = (ln < lim0) ? lane * 8 : (lane & 32) * 8;
            const int off1 = (ln < lim1) ? lane * 8 : (lane & 32) * 8;

            // early-issue inactive-row y-carry load (layers 1-2, inactive rows
            // only): pinned above the staging loads; latency hides under
            // compute; drained by the K-loop's terminal vmcnt(0) (KS=14).
            half4v ycarry{};
            if (carryOwner && brow >= bs)
                ycarry = ldg_llc4(&ybh[(size_t)(pin * 3 + layer - 1) * BH + po]);

            // per-wave A-source pointers for its K-slice (permuted layout:
            // chunk base + kb*64; ks stride 1024; chunk1 (rows 32-63) +512)
            const _Float16 *a0, *a1;
            bool coh;
            if (!isH) {
                if (layer == 0) {  // embedding: read-only, cacheable, row-major
                    const int ko = kb + khalf;
                    a0 = ehi + (size_t)padded_in[ln * Sn + t] * Hn + ko;
                    a1 = ehi + (size_t)padded_in[(32 + ln) * Sn + t] * Hn + ko;
                    coh = false;
                } else {
                    const _Float16* cb =
                        ybh + (size_t)(pin * 3 + layer - 1) * BH + (size_t)kb * 64;
                    a0 = cb + off0;
                    a1 = cb + 512 + off1;
                    coh = true;
                }
            } else {
                const _Float16* cb =
                    hbh + (size_t)(pin * Ln + layer) * BH + (size_t)kb * 64;
                a0 = cb + off0;
                a1 = cb + 512 + off1;
                coh = true;
            }

            // compute; two-phase partial accumulation (waves 0-3 store, 4-7 add)
            if (bs > 32) {
                f32x16 acc[2][2];
                if (coh) cell_compute_lds<2>(a0, a1, s0, s1, lane, wf, acc);
                else cell_compute_plain<2>(a0, a1, wf, acc);
                if (wv < 4) part_write<2, false>(part[wv], acc, lane);
                __syncthreads();
                if (wv >= 4) part_write<2, true>(part[wv - 4], acc, lane);
            } else {
                f32x16 acc[1][2];
                if (coh) cell_compute_lds<1>(a0, a1, s0, s1, lane, wf, acc);
                else cell_compute_plain<1>(a0, a1, wf, acc);
                if (wv < 4) part_write<1, false>(part[wv], acc, lane);
                __syncthreads();
                if (wv >= 4) part_write<1, true>(part[wv - 4], acc, lane);
            }
            __syncthreads();

            if (tid < 256) {
                // cross-wave K-reduction + bias
                float gsum[4][4];
#pragma unroll
                for (int g = 0; g < 4; ++g) {
                    int nidx = (g * 16 + jcol) ^ ((brow & 7) << 2);
                    f32x4 s = *reinterpret_cast<const f32x4*>(&part[0][brow][nidx]);
#pragma unroll
                    for (int p2 = 1; p2 < 4; ++p2)
                        s = s + *reinterpret_cast<const f32x4*>(&part[p2][brow][nidx]);
#pragma unroll
                    for (int p = 0; p < 4; ++p) gsum[g][p] = s[p] + bias[g][p];
                }

                const bool active = (brow < bs);
                float hold[4], ysum[4];
#pragma unroll
                for (int p = 0; p < 4; ++p) {
                    float cn = sigmf(gsum[1][p]) * creg[p] + sigmf(gsum[0][p]) * tanhf_(gsum[2][p]);
                    float hn = sigmf(gsum[3][p]) * tanhf_(cn);
                    hold[p] = hreg[p];
                    if (active) { creg[p] = cn; hreg[p] = hn; }
                    ysum[p] = hreg[p] + hold[p];
                }
                // R11: h broadcast only for ACTIVE rows (inactive h never read).
                if (active) {
                    half4v hh;
#pragma unroll
                    for (int p = 0; p < 4; ++p) hh[p] = (_Float16)hreg[p];
                    stg_coh4(&hbh[(size_t)(pout * Ln + layer) * BH + po], hh);
                }
                if (layer < 3) {  // y interface feed (same-parity slot, permuted) -> LLC
                    half4v yh;
                    if (active) {
#pragma unroll
                        for (int p = 0; p < 4; ++p) yh[p] = (_Float16)ysum[p];
                    } else {  // carry incoming y (x_t for l=0) verbatim
                        if (layer == 0) {
                            int ib = padded_in[brow * Sn + t];
                            yh = *reinterpret_cast<const half4v*>(&ehi[(size_t)ib * Hn + J]);
                        } else {
                            yh = ycarry;  // pre-issued at step start
                        }
                    }
                    stg_coh4(&ybh[(size_t)(pin * 3 + layer) * BH + po], yh);
                }
            }
        }
        grid_barrier(bar, cu, w + 1);
    }

    if (layer == 3 && tid < 256) {
        f32x4 o;
#pragma unroll
        for (int p = 0; p < 4; ++p) o[p] = hreg[p];
        *reinterpret_cast<f32x4*>(&out[(size_t)brow * Hn + J]) = o;
    }
}

extern "C" void kernel_launch(void* const* d_in, const int* in_sizes, int n_in,
                              void* d_out, int out_size, void* d_ws, size_t ws_size,
                              hipStream_t stream) {
    const int* padded_in = (const int*)d_in[0];
    const int* in_lengths = (const int*)d_in[1];
    const float* emb = (const float*)d_in[2];
    const float* w_ih = (const float*)d_in[3];
    const float* w_hh = (const float*)d_in[4];
    const float* b_ih = (const float*)d_in[5];
    const float* b_hh = (const float*)d_in[6];
    float* outp = (float*)d_out;

    // workspace (~2 MB), all segments 16B-aligned
    char* w = (char*)d_ws;
    int* bar = (int*)w;            w += BAR_INTS * 4;
    float* biasf = (float*)w;      w += (size_t)Ln * 4 * Hn * 4;
    _Float16* ehi = (_Float16*)w;  w += (size_t)Vn * Hn * 2;
    _Float16* hbh = (_Float16*)w;  w += (size_t)2 * Ln * Bn * Hn * 2;
    _Float16* ybh = (_Float16*)w;  w += (size_t)2 * 3 * Bn * Hn * 2;

    init_kernel<<<256, 256, 0, stream>>>(b_ih, b_hh, emb, bar, biasf, ehi, hbh);
    lstm_persistent<<<NBLK, 512, 0, stream>>>(padded_in, in_lengths, w_ih, w_hh, biasf, bar,
                                              ehi, hbh, ybh, outp);
}

// Round 16
// 6110.544 us; speedup vs baseline: 2.7212x; 1.0068x over previous
//
#include <hip/hip_runtime.h>
#include <hip/hip_fp16.h>

// EncoderRNN: V=29, H=1024, L=4, B=64, S=512. Inputs/out are FLOAT32 (proven R1/R2).
#define Vn 29
#define Hn 1024
#define Ln 4
#define Bn 64
#define Sn 512
#define BH (Bn * Hn)
#define NBLK 256

typedef _Float16 half8 __attribute__((ext_vector_type(8)));
typedef _Float16 half4v __attribute__((ext_vector_type(4)));
typedef float f32x16 __attribute__((ext_vector_type(16)));
typedef float f32x4 __attribute__((ext_vector_type(4)));

__device__ __forceinline__ float sigmf(float x) { return 1.0f / (1.0f + __expf(-x)); }
__device__ __forceinline__ float tanhf_(float x) { return 1.0f - 2.0f / (__expf(2.0f * x) + 1.0f); }

// Wave-linear permuted layout for h/y interface buffers (we own both sides):
// element (row r, unit j) lives at half-offset
//   ((j>>4)*2 + (r>>5))*512 + (((j>>3)&1)*32 + (r&31))*8 + (j&7)
// K-loop wave-load of one MFMA A-chunk is CONTIGUOUS 1 KB (lane l reads
// base + l*16B; lane l <-> row l&31), full-line epilogue writes. This ALSO
// matches global_load_lds's write pattern (wave-uniform LDS base + lane*16B).
__device__ __forceinline__ int perm_off(int r, int j) {
    return (((j >> 4) * 2 + (r >> 5)) << 9) + ((((j >> 3) & 1) << 5) + (r & 31)) * 8 + (j & 7);
}

// 8B LLC-coherent load, asm-pinned issue point (hoisted y-carry load).
__device__ __forceinline__ half4v ldg_llc4(const _Float16* p) {
    half4v v;
    asm volatile("global_load_dwordx2 %0, %1, off sc0 sc1" : "=v"(v) : "v"(p) : "memory");
    return v;
}

// R13-proven: async global->LDS staging, LLC-coherent (aux=17 = sc0|sc1).
// Global src is per-lane; LDS dst is wave-uniform base + lane*16 (HW rule),
// which our permuted layout matches exactly. Zero VGPR cost per in-flight load.
__device__ __forceinline__ void gld_lds16(const _Float16* g, _Float16* l) {
    __builtin_amdgcn_global_load_lds(
        (const __attribute__((address_space(1))) void*)g,
        (__attribute__((address_space(3))) void*)l, 16, 0, 17);
}

__device__ __forceinline__ void stg_coh4(_Float16* p, half4v v) {
    union { half4v h; unsigned long long u; } c;
    c.h = v;
    __hip_atomic_store((unsigned long long*)p, c.u, __ATOMIC_RELAXED,
                       __HIP_MEMORY_SCOPE_AGENT);
}

// barrier block: c0[8] padded 32 ints apart (0..255), c1 at [256], gen at [288]
#define BAR_INTS 320

__global__ void init_kernel(const float* __restrict__ bi, const float* __restrict__ bh,
                            const float* __restrict__ emb, int* __restrict__ bar,
                            float* __restrict__ biasf, _Float16* __restrict__ ehi,
                            _Float16* __restrict__ hbh) {
    int i = blockIdx.x * blockDim.x + threadIdx.x;
    int stride = gridDim.x * blockDim.x;
    for (int k = i; k < BAR_INTS; k += stride) bar[k] = 0;
    for (int k = i; k < Ln * 4 * Hn; k += stride) biasf[k] = bi[k] + bh[k];
    for (int k = i; k < Vn * Hn; k += stride)
        ehi[k] = (_Float16)((k < Hn) ? 0.f : emb[k]);  // padding_idx=0 row zero
    for (int k = i; k < 2 * Ln * Bn * Hn; k += stride) hbh[k] = (_Float16)0.f;
}

// Grid barrier, R12-proven: atomic-tree shape with deterministic-step
// monotonic counters (no gen pre-load, no reset phase). Do NOT change the
// protocol structure (R9/R10 flag-array redesign faulted twice).
__device__ __forceinline__ void grid_barrier(int* __restrict__ bar, int bid, int step) {
    asm volatile("s_waitcnt vmcnt(0)" ::: "memory");  // drain this wave's stores
    __syncthreads();
    if (threadIdx.x == 0) {
        int* c0 = bar + (bid & 7) * 32;
        int* c1 = bar + 256;
        int* gen = bar + 288;
        bool rel = false;
        int p = __hip_atomic_fetch_add(c0, 1, __ATOMIC_RELAXED, __HIP_MEMORY_SCOPE_AGENT);
        if (p == 32 * step - 1) {  // group's last arrival for this step
            int q = __hip_atomic_fetch_add(c1, 1, __ATOMIC_RELAXED, __HIP_MEMORY_SCOPE_AGENT);
            if (q == 8 * step - 1) {  // grid's last group
                __hip_atomic_store(gen, step, __ATOMIC_RELAXED, __HIP_MEMORY_SCOPE_AGENT);
                rel = true;
            }
        }
        if (!rel) {
            long long t0 = clock64();
            int it = 0;
            while (__hip_atomic_load(gen, __ATOMIC_RELAXED, __HIP_MEMORY_SCOPE_AGENT) < step) {
                __builtin_amdgcn_s_sleep(1);
                if (((++it) & 255) == 0 && clock64() - t0 > 2000000000LL) break;  // escape
            }
        }
    }
    __syncthreads();
}

// ---- R16 K-loop: 10-deep global->LDS pipeline (160KB LDS) + 2-slot LDS->reg
// read-ahead, ORIGINAL chunk order 0..15. R15 lesson: rotation's accumulation
// reorder amplifies fp32 reassociation noise through the 512-step recurrence
// to ~3.7e-3 (2x over threshold) -- summation-order changes are BANNED. This
// round keeps R15's (mechanically validated) depth-10 slot/vmcnt arithmetic
// with bit-identical accumulation order to the proven R13.
// Slot for chunk i = i % 10. Prologue: issue chunks 0..9, wait MT*9, prime.
// Iter KS: wait vmcnt(MT*min(8,14-KS)) -> chunk KS+1 arrived; "memory"
// clobber pins the following ds_read; 4 MFMA on chunk KS; issue chunk KS+10
// into slot KS (its ds_read retired at iter KS-1, lgkm-ordered before this
// iter's MFMAs). Terminal KS=14 -> vmcnt(0), draining ycarry too.
template <int KS, int MT>
struct KStepL {
    static __device__ __forceinline__ void run(const _Float16* a0, const _Float16* a1,
                                               _Float16* s0, _Float16* s1,
                                               int lane, half8 (&x0)[2], half8 (&x1)[2],
                                               const half8 (&wf)[2][16],
                                               f32x16 (&acc)[MT][2]) {
        if constexpr (KS < 15) {
            constexpr int CNT = (14 - KS) < 8 ? (14 - KS) : 8;
            asm volatile("s_waitcnt vmcnt(%0)" :: "i"(MT * CNT) : "memory");
            constexpr int rs = (KS + 1 < 10) ? KS + 1 : KS - 9;
            x0[(KS + 1) & 1] = *reinterpret_cast<const half8*>(s0 + rs * 512 + lane * 8);
            if constexpr (MT == 2)
                x1[(KS + 1) & 1] = *reinterpret_cast<const half8*>(s1 + rs * 512 + lane * 8);
        }
        acc[0][0] = __builtin_amdgcn_mfma_f32_32x32x16_f16(x0[KS & 1], wf[0][KS], acc[0][0], 0, 0, 0);
        acc[0][1] = __builtin_amdgcn_mfma_f32_32x32x16_f16(x0[KS & 1], wf[1][KS], acc[0][1], 0, 0, 0);
        if constexpr (MT == 2) {
            acc[1][0] = __builtin_amdgcn_mfma_f32_32x32x16_f16(x1[KS & 1], wf[0][KS], acc[1][0], 0, 0, 0);
            acc[1][1] = __builtin_amdgcn_mfma_f32_32x32x16_f16(x1[KS & 1], wf[1][KS], acc[1][1], 0, 0, 0);
        }
        if constexpr (KS + 10 < 16) {
            gld_lds16(a0 + (KS + 10) * 1024, s0 + KS * 512);  // slot (KS+10)%10 == KS
            if constexpr (MT == 2) gld_lds16(a1 + (KS + 10) * 1024, s1 + KS * 512);
        }
        KStepL<KS + 1, MT>::run(a0, a1, s0, s1, lane, x0, x1, wf, acc);
    }
};
template <int MT>
struct KStepL<16, MT> {
    static __device__ __forceinline__ void run(const _Float16*, const _Float16*, _Float16*,
                                               _Float16*, int, half8 (&)[2], half8 (&)[2],
                                               const half8 (&)[2][16], f32x16 (&)[MT][2]) {}
};

template <int MT>
__device__ __forceinline__ void cell_compute_lds(const _Float16* a0, const _Float16* a1,
                                                 _Float16* s0, _Float16* s1, int lane,
                                                 const half8 (&wf)[2][16],
                                                 f32x16 (&acc)[MT][2]) {
#pragma unroll
    for (int mt = 0; mt < MT; ++mt)
#pragma unroll
        for (int nt = 0; nt < 2; ++nt)
#pragma unroll
            for (int r = 0; r < 16; ++r) acc[mt][nt][r] = 0.f;
    // prologue: fill all 10 slots, wait slot 0, prime reg window
#pragma unroll
    for (int i = 0; i < 10; ++i) {
        gld_lds16(a0 + i * 1024, s0 + i * 512);
        if constexpr (MT == 2) gld_lds16(a1 + i * 1024, s1 + i * 512);
    }
    asm volatile("s_waitcnt vmcnt(%0)" :: "i"(MT * 9) : "memory");
    half8 x0[2], x1[2];
    x0[0] = *reinterpret_cast<const half8*>(s0 + lane * 8);
    if constexpr (MT == 2) x1[0] = *reinterpret_cast<const half8*>(s1 + lane * 8);
    KStepL<0, MT>::run(a0, a1, s0, s1, lane, x0, x1, wf, acc);
}

// plain-cached path (layer-0 embedding reads, row-major ehi), original order
template <int MT>
__device__ __forceinline__ void cell_compute_plain(const _Float16* __restrict__ a0,
                                                   const _Float16* __restrict__ a1,
                                                   const half8 (&wf)[2][16],
                                                   f32x16 (&acc)[MT][2]) {
#pragma unroll
    for (int mt = 0; mt < MT; ++mt)
#pragma unroll
        for (int nt = 0; nt < 2; ++nt)
#pragma unroll
            for (int r = 0; r < 16; ++r) acc[mt][nt][r] = 0.f;
#pragma unroll
    for (int ks = 0; ks < 16; ++ks) {
        half8 x0 = *reinterpret_cast<const half8*>(a0 + ks * 16);
        acc[0][0] = __builtin_amdgcn_mfma_f32_32x32x16_f16(x0, wf[0][ks], acc[0][0], 0, 0, 0);
        acc[0][1] = __builtin_amdgcn_mfma_f32_32x32x16_f16(x0, wf[1][ks], acc[0][1], 0, 0, 0);
        if constexpr (MT == 2) {
            half8 x1 = *reinterpret_cast<const half8*>(a1 + ks * 16);
            acc[1][0] = __builtin_amdgcn_mfma_f32_32x32x16_f16(x1, wf[0][ks], acc[1][0], 0, 0, 0);
            acc[1][1] = __builtin_amdgcn_mfma_f32_32x32x16_f16(x1, wf[1][ks], acc[1][1], 0, 0, 0);
        }
    }
}

// part write: C layout (32x32): n=lane&31, m=4*(lane>>5)+(r&3)+8*(r>>2)
template <int MT, bool ADD>
__device__ __forceinline__ void part_write(float (*pw)[64], const f32x16 (&acc)[MT][2],
                                           int lane) {
    const int ln = lane & 31;
#pragma unroll
    for (int mt = 0; mt < MT; ++mt)
#pragma unroll
        for (int nt = 0; nt < 2; ++nt)
#pragma unroll
            for (int r = 0; r < 16; ++r) {
                int m = mt * 32 + 4 * (lane >> 5) + (r & 3) + 8 * (r >> 2);
                int n = nt * 32 + ln;
                int idx = n ^ ((m & 7) << 2);
                if (ADD) pw[m][idx] += acc[mt][nt][r];
                else pw[m][idx] = acc[mt][nt][r];
            }
}

// Persistent wavefront LSTM: 256 blocks x 512 threads (8 waves, 1 block/CU).
// Wave w: K-slice 256 (w<4: y/w_ih, w>=4: h/w_hh), full N=64.
// LDS 160KB: per-wave 20KB region = 2 chains x 10 slots x 1KB. part row
// p (16KB, [64][64] f32) aliases wave p's OWN region's first 16KB only
// (20480B stride), so same-wave program order keeps the alias race-free
// (terminal vmcnt(0) drains all LDS-writes before part_write); cross-wave
// part accesses are fenced by the existing __syncthreads pair.
__global__ __launch_bounds__(512, 2) void lstm_persistent(
    const int* __restrict__ padded_in, const int* __restrict__ in_lengths,
    const float* __restrict__ w_ih, const float* __restrict__ w_hh,
    const float* __restrict__ biasf, int* __restrict__ bar,
    const _Float16* __restrict__ ehi, _Float16* __restrict__ hbh,
    _Float16* __restrict__ ybh, float* __restrict__ out) {
    __shared__ __align__(1024) char ldsbuf[163840];

    const int cu = blockIdx.x;
    const int layer = cu >> 6;
    const int j0 = (cu & 63) * 16;
    const int tid = threadIdx.x;
    const int wv = tid >> 6;
    const int lane = tid & 63;
    const int ln = lane & 31;
    const int khalf = (lane >> 5) * 8;
    const bool isH = (wv >= 4);
    const int kb = (isH ? (wv - 4) : wv) * 256;

    // this wave's LDS stage bases (halves): 10240 halves/wave, chain stride 5120
    _Float16* s0 = reinterpret_cast<_Float16*>(ldsbuf) + wv * 10240;
    _Float16* s1 = s0 + 5120;

    // ---- one-time weight preload: fp32 -> fp16 frags, 128 regs/lane
    half8 wf[2][16];
    {
        const float* wsrc = isH ? w_hh : w_ih;
#pragma unroll
        for (int nt = 0; nt < 2; ++nt) {
            int n = nt * 32 + ln;
            const float* rowp =
                wsrc + ((size_t)layer * 4 * Hn + (n >> 4) * Hn + j0 + (n & 15)) * Hn + kb + khalf;
#pragma unroll
            for (int ks = 0; ks < 16; ++ks) {
                f32x4 a = *reinterpret_cast<const f32x4*>(rowp + ks * 16);
                f32x4 b = *reinterpret_cast<const f32x4*>(rowp + ks * 16 + 4);
                half8 h;
                h[0] = (_Float16)a[0]; h[1] = (_Float16)a[1];
                h[2] = (_Float16)a[2]; h[3] = (_Float16)a[3];
                h[4] = (_Float16)b[0]; h[5] = (_Float16)b[1];
                h[6] = (_Float16)b[2]; h[7] = (_Float16)b[3];
                wf[nt][ks] = h;
            }
        }
    }

    // epilogue ownership (threads 0..255): batch row brow, 4 units jcol..jcol+3
    const int brow = (tid & 255) >> 2;
    const int jcol = (tid & 3) * 4;
    const int J = j0 + jcol;
    const int po = perm_off(brow, J);  // loop-invariant permuted half-offset
    float bias[4][4];
#pragma unroll
    for (int g = 0; g < 4; ++g)
#pragma unroll
        for (int p = 0; p < 4; ++p)
            bias[g][p] = biasf[layer * 4096 + g * 1024 + J + p];

    float creg[4] = {0.f, 0.f, 0.f, 0.f};
    float hreg[4] = {0.f, 0.f, 0.f, 0.f};

    const bool carryOwner = (tid < 256) && (layer > 0) && (layer < 3);

    for (int w = 0; w < Sn + Ln - 1; ++w) {
        const int t = w - layer;
        if (t >= 0 && t < Sn) {
            const int bs = in_lengths[t];
            const int pin = t & 1;
            const int pout = pin ^ 1;

            // R8 exact row masking: rows >= bs produce DISCARDED gates (sorted
            // lengths -> active rows are a prefix). Redirect inactive lanes
            // (lane l <-> row l&31 in the permuted chunk) to the chunk's row 0;
            // redirected lanes coalesce onto already-fetched lines, so LLC
            // interface bytes ~ bs exactly.
            const int lim0 = bs < 32 ? bs : 32;
            const int lim1 = bs - 32;  // only consumed when MT==2 (bs>32)
            const int off0 = (ln < lim0) ? lane * 8 : (lane & 32) * 8;
            const int off1 = (ln < lim1) ? lane * 8 : (lane & 32) * 8;

            // early-issue inactive-row y-carry load (layers 1-2, inactive rows
            // only): pinned above the staging loads; latency hides under
            // compute; drained by the K-loop's terminal vmcnt(0) (KS=14).
            half4v ycarry{};
            if (carryOwner && brow >= bs)
                ycarry = ldg_llc4(&ybh[(size_t)(pin * 3 + layer - 1) * BH + po]);

            // per-wave A-source pointers for its K-slice (permuted layout:
            // chunk base + kb*64; ks stride 1024; chunk1 (rows 32-63) +512)
            const _Float16 *a0, *a1;
            bool coh;
            if (!isH) {
                if (layer == 0) {  // embedding: read-only, cacheable, row-major
                    const int ko = kb + khalf;
                    a0 = ehi + (size_t)padded_in[ln * Sn + t] * Hn + ko;
                    a1 = ehi + (size_t)padded_in[(32 + ln) * Sn + t] * Hn + ko;
                    coh = false;
                } else {
                    const _Float16* cb =
                        ybh + (size_t)(pin * 3 + layer - 1) * BH + (size_t)kb * 64;
                    a0 = cb + off0;
                    a1 = cb + 512 + off1;
                    coh = true;
                }
            } else {
                const _Float16* cb =
                    hbh + (size_t)(pin * Ln + layer) * BH + (size_t)kb * 64;
                a0 = cb + off0;
                a1 = cb + 512 + off1;
                coh = true;
            }

            // compute; two-phase partial accumulation (waves 0-3 store, 4-7 add)
            if (bs > 32) {
                f32x16 acc[2][2];
                if (coh) cell_compute_lds<2>(a0, a1, s0, s1, lane, wf, acc);
                else cell_compute_plain<2>(a0, a1, wf, acc);
                if (wv < 4)
                    part_write<2, false>(
                        reinterpret_cast<float (*)[64]>(ldsbuf + (size_t)wv * 20480), acc, lane);
                __syncthreads();
                if (wv >= 4)
                    part_write<2, true>(
                        reinterpret_cast<float (*)[64]>(ldsbuf + (size_t)(wv - 4) * 20480), acc,
                        lane);
            } else {
                f32x16 acc[1][2];
                if (coh) cell_compute_lds<1>(a0, a1, s0, s1, lane, wf, acc);
                else cell_compute_plain<1>(a0, a1, wf, acc);
                if (wv < 4)
                    part_write<1, false>(
                        reinterpret_cast<float (*)[64]>(ldsbuf + (size_t)wv * 20480), acc, lane);
                __syncthreads();
                if (wv >= 4)
                    part_write<1, true>(
                        reinterpret_cast<float (*)[64]>(ldsbuf + (size_t)(wv - 4) * 20480), acc,
                        lane);
            }
            __syncthreads();

            if (tid < 256) {
                // cross-wave K-reduction + bias (part regions at 20480B stride)
                float gsum[4][4];
#pragma unroll
                for (int g = 0; g < 4; ++g) {
                    int nidx = (g * 16 + jcol) ^ ((brow & 7) << 2);
                    const char* pb = ldsbuf + (size_t)brow * 256 + (size_t)nidx * 4;
                    f32x4 s = *reinterpret_cast<const f32x4*>(pb);
#pragma unroll
                    for (int p2 = 1; p2 < 4; ++p2)
                        s = s + *reinterpret_cast<const f32x4*>(pb + (size_t)p2 * 20480);
#pragma unroll
                    for (int p = 0; p < 4; ++p) gsum[g][p] = s[p] + bias[g][p];
                }

                const bool active = (brow < bs);
                float hold[4], ysum[4];
#pragma unroll
                for (int p = 0; p < 4; ++p) {
                    float cn = sigmf(gsum[1][p]) * creg[p] + sigmf(gsum[0][p]) * tanhf_(gsum[2][p]);
                    float hn = sigmf(gsum[3][p]) * tanhf_(cn);
                    hold[p] = hreg[p];
                    if (active) { creg[p] = cn; hreg[p] = hn; }
                    ysum[p] = hreg[p] + hold[p];
                }
                // R11: h broadcast only for ACTIVE rows (inactive h never read).
                if (active) {
                    half4v hh;
#pragma unroll
                    for (int p = 0; p < 4; ++p) hh[p] = (_Float16)hreg[p];
                    stg_coh4(&hbh[(size_t)(pout * Ln + layer) * BH + po], hh);
                }
                if (layer < 3) {  // y interface feed (same-parity slot, permuted) -> LLC
                    half4v yh;
                    if (active) {
#pragma unroll
                        for (int p = 0; p < 4; ++p) yh[p] = (_Float16)ysum[p];
                    } else {  // carry incoming y (x_t for l=0) verbatim
                        if (layer == 0) {
                            int ib = padded_in[brow * Sn + t];
                            yh = *reinterpret_cast<const half4v*>(&ehi[(size_t)ib * Hn + J]);
                        } else {
                            yh = ycarry;  // pre-issued at step start
                        }
                    }
                    stg_coh4(&ybh[(size_t)(pin * 3 + layer) * BH + po], yh);
                }
            }
        }
        grid_barrier(bar, cu, w + 1);
    }

    if (layer == 3 && tid < 256) {
        f32x4 o;
#pragma unroll
        for (int p = 0; p < 4; ++p) o[p] = hreg[p];
        *reinterpret_cast<f32x4*>(&out[(size_t)brow * Hn + J]) = o;
    }
}

extern "C" void kernel_launch(void* const* d_in, const int* in_sizes, int n_in,
                              void* d_out, int out_size, void* d_ws, size_t ws_size,
                              hipStream_t stream) {
    const int* padded_in = (const int*)d_in[0];
    const int* in_lengths = (const int*)d_in[1];
    const float* emb = (const float*)d_in[2];
    const float* w_ih = (const float*)d_in[3];
    const float* w_hh = (const float*)d_in[4];
    const float* b_ih = (const float*)d_in[5];
    const float* b_hh = (const float*)d_in[6];
    float* outp = (float*)d_out;

    // workspace (~2 MB), all segments 16B-aligned
    char* w = (char*)d_ws;
    int* bar = (int*)w;            w += BAR_INTS * 4;
    float* biasf = (float*)w;      w += (size_t)Ln * 4 * Hn * 4;
    _Float16* ehi = (_Float16*)w;  w += (size_t)Vn * Hn * 2;
    _Float16* hbh = (_Float16*)w;  w += (size_t)2 * Ln * Bn * Hn * 2;
    _Float16* ybh = (_Float16*)w;  w += (size_t)2 * 3 * Bn * Hn * 2;

    init_kernel<<<256, 256, 0, stream>>>(b_ih, b_hh, emb, bar, biasf, ehi, hbh);
    lstm_persistent<<<NBLK, 512, 0, stream>>>(padded_in, in_lengths, w_ih, w_hh, biasf, bar,
                                              ehi, hbh, ybh, outp);
}

// Round 17
// 5726.979 us; speedup vs baseline: 2.9035x; 1.0670x over previous
//
#include <hip/hip_runtime.h>
#include <hip/hip_fp16.h>

// EncoderRNN: V=29, H=1024, L=4, B=64, S=512. Inputs/out are FLOAT32 (proven R1/R2).
#define Vn 29
#define Hn 1024
#define Ln 4
#define Bn 64
#define Sn 512
#define BH (Bn * Hn)
#define NBLK 256

typedef _Float16 half8 __attribute__((ext_vector_type(8)));
typedef float f32x16 __attribute__((ext_vector_type(16)));
typedef float f32x4 __attribute__((ext_vector_type(4)));
typedef float f32x2 __attribute__((ext_vector_type(2)));

__device__ __forceinline__ float sigmf(float x) { return 1.0f / (1.0f + __expf(-x)); }
__device__ __forceinline__ float tanhf_(float x) { return 1.0f - 2.0f / (__expf(2.0f * x) + 1.0f); }

// Wave-linear permuted layout for h/y interface buffers (we own both sides):
// element (row r, unit j) lives at half-offset
//   ((j>>4)*2 + (r>>5))*512 + (((j>>3)&1)*32 + (r&31))*8 + (j&7)
// K-loop wave-load of one MFMA A-chunk is CONTIGUOUS 1 KB (lane l reads
// base + l*16B; lane l <-> row l&31), full-line epilogue writes. This ALSO
// matches global_load_lds's write pattern (wave-uniform LDS base + lane*16B).
__device__ __forceinline__ int perm_off(int r, int j) {
    return (((j >> 4) * 2 + (r >> 5)) << 9) + ((((j >> 3) & 1) << 5) + (r & 31)) * 8 + (j & 7);
}

// 4B LLC-coherent load, asm-pinned issue point (hoisted y-carry load, 2 units).
__device__ __forceinline__ unsigned int ldg_llc2(const _Float16* p) {
    unsigned int v;
    asm volatile("global_load_dword %0, %1, off sc0 sc1" : "=v"(v) : "v"(p) : "memory");
    return v;
}

// R13-proven: async global->LDS staging, LLC-coherent (aux=17 = sc0|sc1).
// Global src is per-lane; LDS dst is wave-uniform base + lane*16 (HW rule),
// which our permuted layout matches exactly. Zero VGPR cost per in-flight load.
__device__ __forceinline__ void gld_lds16(const _Float16* g, _Float16* l) {
    __builtin_amdgcn_global_load_lds(
        (const __attribute__((address_space(1))) void*)g,
        (__attribute__((address_space(3))) void*)l, 16, 0, 17);
}

// 4B coherent store (epilogue now owns 2 units/thread).
__device__ __forceinline__ void stg_coh2(_Float16* p, _Float16 a, _Float16 b) {
    union { _Float16 h[2]; unsigned int u; } c;
    c.h[0] = a; c.h[1] = b;
    __hip_atomic_store((unsigned int*)p, c.u, __ATOMIC_RELAXED, __HIP_MEMORY_SCOPE_AGENT);
}

// barrier block: c0[8] padded 32 ints apart (0..255), c1 at [256], gen at [288]
#define BAR_INTS 320

__global__ void init_kernel(const float* __restrict__ bi, const float* __restrict__ bh,
                            const float* __restrict__ emb, int* __restrict__ bar,
                            float* __restrict__ biasf, _Float16* __restrict__ ehi,
                            _Float16* __restrict__ hbh) {
    int i = blockIdx.x * blockDim.x + threadIdx.x;
    int stride = gridDim.x * blockDim.x;
    for (int k = i; k < BAR_INTS; k += stride) bar[k] = 0;
    for (int k = i; k < Ln * 4 * Hn; k += stride) biasf[k] = bi[k] + bh[k];
    for (int k = i; k < Vn * Hn; k += stride)
        ehi[k] = (_Float16)((k < Hn) ? 0.f : emb[k]);  // padding_idx=0 row zero
    for (int k = i; k < 2 * Ln * Bn * Hn; k += stride) hbh[k] = (_Float16)0.f;
}

// Grid barrier, R12-proven: atomic-tree shape with deterministic-step
// monotonic counters (no gen pre-load, no reset phase). Do NOT change the
// protocol structure (R9/R10 flag-array redesign faulted twice).
__device__ __forceinline__ void grid_barrier(int* __restrict__ bar, int bid, int step) {
    asm volatile("s_waitcnt vmcnt(0)" ::: "memory");  // drain this wave's stores
    __syncthreads();
    if (threadIdx.x == 0) {
        int* c0 = bar + (bid & 7) * 32;
        int* c1 = bar + 256;
        int* gen = bar + 288;
        bool rel = false;
        int p = __hip_atomic_fetch_add(c0, 1, __ATOMIC_RELAXED, __HIP_MEMORY_SCOPE_AGENT);
        if (p == 32 * step - 1) {  // group's last arrival for this step
            int q = __hip_atomic_fetch_add(c1, 1, __ATOMIC_RELAXED, __HIP_MEMORY_SCOPE_AGENT);
            if (q == 8 * step - 1) {  // grid's last group
                __hip_atomic_store(gen, step, __ATOMIC_RELAXED, __HIP_MEMORY_SCOPE_AGENT);
                rel = true;
            }
        }
        if (!rel) {
            long long t0 = clock64();
            int it = 0;
            while (__hip_atomic_load(gen, __ATOMIC_RELAXED, __HIP_MEMORY_SCOPE_AGENT) < step) {
                __builtin_amdgcn_s_sleep(1);
                if (((++it) & 255) == 0 && clock64() - t0 > 2000000000LL) break;  // escape
            }
        }
    }
    __syncthreads();
}

// ---- MT=2 K-loop (R16-proven): 10-deep global->LDS pipeline, 2-slot LDS->reg
// read-ahead, original chunk order 0..15 (R15 lesson: summation-order changes
// are BANNED -- reassociation noise amplifies ~1000x through the recurrence).
template <int KS>
struct KStepL {
    static __device__ __forceinline__ void run(const _Float16* a0, const _Float16* a1,
                                               _Float16* s0, _Float16* s1,
                                               int lane, half8 (&x0)[2], half8 (&x1)[2],
                                               const half8 (&wf)[2][16],
                                               f32x16 (&acc)[2][2]) {
        if constexpr (KS < 15) {
            constexpr int CNT = (14 - KS) < 8 ? (14 - KS) : 8;
            asm volatile("s_waitcnt vmcnt(%0)" :: "i"(2 * CNT) : "memory");
            constexpr int rs = (KS + 1 < 10) ? KS + 1 : KS - 9;
            x0[(KS + 1) & 1] = *reinterpret_cast<const half8*>(s0 + rs * 512 + lane * 8);
            x1[(KS + 1) & 1] = *reinterpret_cast<const half8*>(s1 + rs * 512 + lane * 8);
        }
        acc[0][0] = __builtin_amdgcn_mfma_f32_32x32x16_f16(x0[KS & 1], wf[0][KS], acc[0][0], 0, 0, 0);
        acc[0][1] = __builtin_amdgcn_mfma_f32_32x32x16_f16(x0[KS & 1], wf[1][KS], acc[0][1], 0, 0, 0);
        acc[1][0] = __builtin_amdgcn_mfma_f32_32x32x16_f16(x1[KS & 1], wf[0][KS], acc[1][0], 0, 0, 0);
        acc[1][1] = __builtin_amdgcn_mfma_f32_32x32x16_f16(x1[KS & 1], wf[1][KS], acc[1][1], 0, 0, 0);
        if constexpr (KS + 10 < 16) {
            gld_lds16(a0 + (KS + 10) * 1024, s0 + KS * 512);  // slot (KS+10)%10 == KS
            gld_lds16(a1 + (KS + 10) * 1024, s1 + KS * 512);
        }
        KStepL<KS + 1>::run(a0, a1, s0, s1, lane, x0, x1, wf, acc);
    }
};
template <>
struct KStepL<16> {
    static __device__ __forceinline__ void run(const _Float16*, const _Float16*, _Float16*,
                                               _Float16*, int, half8 (&)[2], half8 (&)[2],
                                               const half8 (&)[2][16], f32x16 (&)[2][2]) {}
};

// ---- R17 MT=1 K-loop: FULL 16-chunk prefetch (chain s1 unused when bs<=32;
// its 10 slots are contiguous after s0's, giving 20 slots -> all 16 chunks in
// flight, zero mid-loop issues). Same chunk order -> identical numerics.
// vmcnt: prologue 16 issues, wait 15 (ycarry-in-flight only stricter);
// iter KS<15 waits 14-KS -> chunk KS+1 arrived; KS=14 -> vmcnt(0) drains all.
template <int KS>
struct KStepF {
    static __device__ __forceinline__ void run(_Float16* s0, int lane, half8 (&x0)[2],
                                               const half8 (&wf)[2][16], f32x16 (&acc)[1][2]) {
        if constexpr (KS < 15) {
            asm volatile("s_waitcnt vmcnt(%0)" :: "i"(14 - KS) : "memory");
            x0[(KS + 1) & 1] = *reinterpret_cast<const half8*>(s0 + (KS + 1) * 512 + lane * 8);
        }
        acc[0][0] = __builtin_amdgcn_mfma_f32_32x32x16_f16(x0[KS & 1], wf[0][KS], acc[0][0], 0, 0, 0);
        acc[0][1] = __builtin_amdgcn_mfma_f32_32x32x16_f16(x0[KS & 1], wf[1][KS], acc[0][1], 0, 0, 0);
        KStepF<KS + 1>::run(s0, lane, x0, wf, acc);
    }
};
template <>
struct KStepF<16> {
    static __device__ __forceinline__ void run(_Float16*, int, half8 (&)[2],
                                               const half8 (&)[2][16], f32x16 (&)[1][2]) {}
};

template <int MT>
__device__ __forceinline__ void cell_compute_lds(const _Float16* a0, const _Float16* a1,
                                                 _Float16* s0, _Float16* s1, int lane,
                                                 const half8 (&wf)[2][16],
                                                 f32x16 (&acc)[MT][2]) {
#pragma unroll
    for (int mt = 0; mt < MT; ++mt)
#pragma unroll
        for (int nt = 0; nt < 2; ++nt)
#pragma unroll
            for (int r = 0; r < 16; ++r) acc[mt][nt][r] = 0.f;
    if constexpr (MT == 2) {
        // prologue: fill all 10 slot-pairs, wait slot-pair 0, prime reg window
#pragma unroll
        for (int i = 0; i < 10; ++i) {
            gld_lds16(a0 + i * 1024, s0 + i * 512);
            gld_lds16(a1 + i * 1024, s1 + i * 512);
        }
        asm volatile("s_waitcnt vmcnt(18)" ::: "memory");
        half8 x0[2], x1[2];
        x0[0] = *reinterpret_cast<const half8*>(s0 + lane * 8);
        x1[0] = *reinterpret_cast<const half8*>(s1 + lane * 8);
        KStepL<0>::run(a0, a1, s0, s1, lane, x0, x1, wf, acc);
    } else {
        // full prefetch: all 16 chunks into the contiguous 20-slot region
#pragma unroll
        for (int i = 0; i < 16; ++i) gld_lds16(a0 + i * 1024, s0 + i * 512);
        asm volatile("s_waitcnt vmcnt(15)" ::: "memory");
        half8 x0[2];
        x0[0] = *reinterpret_cast<const half8*>(s0 + lane * 8);
        KStepF<0>::run(s0, lane, x0, wf, acc);
    }
}

// plain-cached path (layer-0 embedding reads, row-major ehi), original order
template <int MT>
__device__ __forceinline__ void cell_compute_plain(const _Float16* __restrict__ a0,
                                                   const _Float16* __restrict__ a1,
                                                   const half8 (&wf)[2][16],
                                                   f32x16 (&acc)[MT][2]) {
#pragma unroll
    for (int mt = 0; mt < MT; ++mt)
#pragma unroll
        for (int nt = 0; nt < 2; ++nt)
#pragma unroll
            for (int r = 0; r < 16; ++r) acc[mt][nt][r] = 0.f;
#pragma unroll
    for (int ks = 0; ks < 16; ++ks) {
        half8 x0 = *reinterpret_cast<const half8*>(a0 + ks * 16);
        acc[0][0] = __builtin_amdgcn_mfma_f32_32x32x16_f16(x0, wf[0][ks], acc[0][0], 0, 0, 0);
        acc[0][1] = __builtin_amdgcn_mfma_f32_32x32x16_f16(x0, wf[1][ks], acc[0][1], 0, 0, 0);
        if constexpr (MT == 2) {
            half8 x1 = *reinterpret_cast<const half8*>(a1 + ks * 16);
            acc[1][0] = __builtin_amdgcn_mfma_f32_32x32x16_f16(x1, wf[0][ks], acc[1][0], 0, 0, 0);
            acc[1][1] = __builtin_amdgcn_mfma_f32_32x32x16_f16(x1, wf[1][ks], acc[1][1], 0, 0, 0);
        }
    }
}

// part write: C layout (32x32): n=lane&31, m=4*(lane>>5)+(r&3)+8*(r>>2)
template <int MT, bool ADD>
__device__ __forceinline__ void part_write(float (*pw)[64], const f32x16 (&acc)[MT][2],
                                           int lane) {
    const int ln = lane & 31;
#pragma unroll
    for (int mt = 0; mt < MT; ++mt)
#pragma unroll
        for (int nt = 0; nt < 2; ++nt)
#pragma unroll
            for (int r = 0; r < 16; ++r) {
                int m = mt * 32 + 4 * (lane >> 5) + (r & 3) + 8 * (r >> 2);
                int n = nt * 32 + ln;
                int idx = n ^ ((m & 7) << 2);
                if (ADD) pw[m][idx] += acc[mt][nt][r];
                else pw[m][idx] = acc[mt][nt][r];
            }
}

// Persistent wavefront LSTM: 256 blocks x 512 threads (8 waves, 1 block/CU).
// Wave w: K-slice 256 (w<4: y/w_ih, w>=4: h/w_hh), full N=64.
// LDS 160KB: per-wave 20KB region = 2 chains x 10 slots x 1KB. part row
// p (16KB, [64][64] f32) aliases wave p's OWN region's first 16KB only
// (20480B stride), so same-wave program order keeps the alias race-free
// (terminal vmcnt(0) drains all LDS-writes before part_write); cross-wave
// part accesses are fenced by the existing __syncthreads pair.
// R17: epilogue spread across ALL 512 threads (2 units/thread) -- elementwise
// math and reduce order are unchanged, so numerics are bit-identical.
__global__ __launch_bounds__(512, 2) void lstm_persistent(
    const int* __restrict__ padded_in, const int* __restrict__ in_lengths,
    const float* __restrict__ w_ih, const float* __restrict__ w_hh,
    const float* __restrict__ biasf, int* __restrict__ bar,
    const _Float16* __restrict__ ehi, _Float16* __restrict__ hbh,
    _Float16* __restrict__ ybh, float* __restrict__ out) {
    __shared__ __align__(1024) char ldsbuf[163840];

    const int cu = blockIdx.x;
    const int layer = cu >> 6;
    const int j0 = (cu & 63) * 16;
    const int tid = threadIdx.x;
    const int wv = tid >> 6;
    const int lane = tid & 63;
    const int ln = lane & 31;
    const int khalf = (lane >> 5) * 8;
    const bool isH = (wv >= 4);
    const int kb = (isH ? (wv - 4) : wv) * 256;

    // this wave's LDS stage bases (halves): 10240 halves/wave, chain stride 5120
    _Float16* s0 = reinterpret_cast<_Float16*>(ldsbuf) + wv * 10240;
    _Float16* s1 = s0 + 5120;

    // ---- one-time weight preload: fp32 -> fp16 frags, 128 regs/lane
    half8 wf[2][16];
    {
        const float* wsrc = isH ? w_hh : w_ih;
#pragma unroll
        for (int nt = 0; nt < 2; ++nt) {
            int n = nt * 32 + ln;
            const float* rowp =
                wsrc + ((size_t)layer * 4 * Hn + (n >> 4) * Hn + j0 + (n & 15)) * Hn + kb + khalf;
#pragma unroll
            for (int ks = 0; ks < 16; ++ks) {
                f32x4 a = *reinterpret_cast<const f32x4*>(rowp + ks * 16);
                f32x4 b = *reinterpret_cast<const f32x4*>(rowp + ks * 16 + 4);
                half8 h;
                h[0] = (_Float16)a[0]; h[1] = (_Float16)a[1];
                h[2] = (_Float16)a[2]; h[3] = (_Float16)a[3];
                h[4] = (_Float16)b[0]; h[5] = (_Float16)b[1];
                h[6] = (_Float16)b[2]; h[7] = (_Float16)b[3];
                wf[nt][ks] = h;
            }
        }
    }

    // R17 epilogue ownership (ALL 512 threads): batch row brow = tid>>3,
    // 2 units jcol..jcol+1 (jcol = (tid&7)*2)
    const int brow = tid >> 3;
    const int jcol = (tid & 7) * 2;
    const int J = j0 + jcol;
    const int po = perm_off(brow, J);  // loop-invariant permuted half-offset (even)
    float bias[4][2];
#pragma unroll
    for (int g = 0; g < 4; ++g)
#pragma unroll
        for (int p = 0; p < 2; ++p)
            bias[g][p] = biasf[layer * 4096 + g * 1024 + J + p];

    float creg[2] = {0.f, 0.f};
    float hreg[2] = {0.f, 0.f};

    const bool carryOwner = (layer > 0) && (layer < 3);

    for (int w = 0; w < Sn + Ln - 1; ++w) {
        const int t = w - layer;
        if (t >= 0 && t < Sn) {
            const int bs = in_lengths[t];
            const int pin = t & 1;
            const int pout = pin ^ 1;

            // R8 exact row masking: rows >= bs produce DISCARDED gates (sorted
            // lengths -> active rows are a prefix). Redirect inactive lanes
            // (lane l <-> row l&31 in the permuted chunk) to the chunk's row 0;
            // redirected lanes coalesce onto already-fetched lines, so LLC
            // interface bytes ~ bs exactly.
            const int lim0 = bs < 32 ? bs : 32;
            const int lim1 = bs - 32;  // only consumed when MT==2 (bs>32)
            const int off0 = (ln < lim0) ? lane * 8 : (lane & 32) * 8;
            const int off1 = (ln < lim1) ? lane * 8 : (lane & 32) * 8;

            // early-issue inactive-row y-carry load (layers 1-2, inactive rows
            // only): pinned above the staging loads; latency hides under
            // compute; drained by the K-loop's terminal vmcnt(0) (KS=14).
            unsigned int ycarry = 0;
            if (carryOwner && brow >= bs)
                ycarry = ldg_llc2(&ybh[(size_t)(pin * 3 + layer - 1) * BH + po]);

            // per-wave A-source pointers for its K-slice (permuted layout:
            // chunk base + kb*64; ks stride 1024; chunk1 (rows 32-63) +512)
            const _Float16 *a0, *a1;
            bool coh;
            if (!isH) {
                if (layer == 0) {  // embedding: read-only, cacheable, row-major
                    const int ko = kb + khalf;
                    a0 = ehi + (size_t)padded_in[ln * Sn + t] * Hn + ko;
                    a1 = ehi + (size_t)padded_in[(32 + ln) * Sn + t] * Hn + ko;
                    coh = false;
                } else {
                    const _Float16* cb =
                        ybh + (size_t)(pin * 3 + layer - 1) * BH + (size_t)kb * 64;
                    a0 = cb + off0;
                    a1 = cb + 512 + off1;
                    coh = true;
                }
            } else {
                const _Float16* cb =
                    hbh + (size_t)(pin * Ln + layer) * BH + (size_t)kb * 64;
                a0 = cb + off0;
                a1 = cb + 512 + off1;
                coh = true;
            }

            // compute; two-phase partial accumulation (waves 0-3 store, 4-7 add)
            if (bs > 32) {
                f32x16 acc[2][2];
                if (coh) cell_compute_lds<2>(a0, a1, s0, s1, lane, wf, acc);
                else cell_compute_plain<2>(a0, a1, wf, acc);
                if (wv < 4)
                    part_write<2, false>(
                        reinterpret_cast<float (*)[64]>(ldsbuf + (size_t)wv * 20480), acc, lane);
                __syncthreads();
                if (wv >= 4)
                    part_write<2, true>(
                        reinterpret_cast<float (*)[64]>(ldsbuf + (size_t)(wv - 4) * 20480), acc,
                        lane);
            } else {
                f32x16 acc[1][2];
                if (coh) cell_compute_lds<1>(a0, a1, s0, s1, lane, wf, acc);
                else cell_compute_plain<1>(a0, a1, wf, acc);
                if (wv < 4)
                    part_write<1, false>(
                        reinterpret_cast<float (*)[64]>(ldsbuf + (size_t)wv * 20480), acc, lane);
                __syncthreads();
                if (wv >= 4)
                    part_write<1, true>(
                        reinterpret_cast<float (*)[64]>(ldsbuf + (size_t)(wv - 4) * 20480), acc,
                        lane);
            }
            __syncthreads();

            {
                // cross-wave K-reduction + bias (part regions at 20480B stride).
                // Elementwise order identical to R16: ((p0+p1)+p2)+p3 + bias.
                float gsum[4][2];
#pragma unroll
                for (int g = 0; g < 4; ++g) {
                    int nidx = (g * 16 + jcol) ^ ((brow & 7) << 2);
                    const char* pb = ldsbuf + (size_t)brow * 256 + (size_t)nidx * 4;
                    f32x2 s = *reinterpret_cast<const f32x2*>(pb);
#pragma unroll
                    for (int p2 = 1; p2 < 4; ++p2)
                        s = s + *reinterpret_cast<const f32x2*>(pb + (size_t)p2 * 20480);
#pragma unroll
                    for (int p = 0; p < 2; ++p) gsum[g][p] = s[p] + bias[g][p];
                }

                const bool active = (brow < bs);
                float hold[2], ysum[2];
#pragma unroll
                for (int p = 0; p < 2; ++p) {
                    float cn = sigmf(gsum[1][p]) * creg[p] + sigmf(gsum[0][p]) * tanhf_(gsum[2][p]);
                    float hn = sigmf(gsum[3][p]) * tanhf_(cn);
                    hold[p] = hreg[p];
                    if (active) { creg[p] = cn; hreg[p] = hn; }
                    ysum[p] = hreg[p] + hold[p];
                }
                // R11: h broadcast only for ACTIVE rows (inactive h never read).
                if (active) {
                    stg_coh2(&hbh[(size_t)(pout * Ln + layer) * BH + po],
                             (_Float16)hreg[0], (_Float16)hreg[1]);
                }
                if (layer < 3) {  // y interface feed (same-parity slot, permuted) -> LLC
                    if (active) {
                        stg_coh2(&ybh[(size_t)(pin * 3 + layer) * BH + po],
                                 (_Float16)ysum[0], (_Float16)ysum[1]);
                    } else {  // carry incoming y (x_t for l=0) verbatim
                        unsigned int u;
                        if (layer == 0) {
                            int ib = padded_in[brow * Sn + t];
                            u = *reinterpret_cast<const unsigned int*>(&ehi[(size_t)ib * Hn + J]);
                        } else {
                            u = ycarry;  // pre-issued at step start
                        }
                        __hip_atomic_store(
                            (unsigned int*)&ybh[(size_t)(pin * 3 + layer) * BH + po], u,
                            __ATOMIC_RELAXED, __HIP_MEMORY_SCOPE_AGENT);
                    }
                }
            }
        }
        grid_barrier(bar, cu, w + 1);
    }

    if (layer == 3) {
        f32x2 o;
        o[0] = hreg[0];
        o[1] = hreg[1];
        *reinterpret_cast<f32x2*>(&out[(size_t)brow * Hn + J]) = o;
    }
}

extern "C" void kernel_launch(void* const* d_in, const int* in_sizes, int n_in,
                              void* d_out, int out_size, void* d_ws, size_t ws_size,
                              hipStream_t stream) {
    const int* padded_in = (const int*)d_in[0];
    const int* in_lengths = (const int*)d_in[1];
    const float* emb = (const float*)d_in[2];
    const float* w_ih = (const float*)d_in[3];
    const float* w_hh = (const float*)d_in[4];
    const float* b_ih = (const float*)d_in[5];
    const float* b_hh = (const float*)d_in[6];
    float* outp = (float*)d_out;

    // workspace (~2 MB), all segments 16B-aligned
    char* w = (char*)d_ws;
    int* bar = (int*)w;            w += BAR_INTS * 4;
    float* biasf = (float*)w;      w += (size_t)Ln * 4 * Hn * 4;
    _Float16* ehi = (_Float16*)w;  w += (size_t)Vn * Hn * 2;
    _Float16* hbh = (_Float16*)w;  w += (size_t)2 * Ln * Bn * Hn * 2;
    _Float16* ybh = (_Float16*)w;  w += (size_t)2 * 3 * Bn * Hn * 2;

    init_kernel<<<256, 256, 0, stream>>>(b_ih, b_hh, emb, bar, biasf, ehi, hbh);
    lstm_persistent<<<NBLK, 512, 0, stream>>>(padded_in, in_lengths, w_ih, w_hh, biasf, bar,
                                              ehi, hbh, ybh, outp);
}